// Round 2
// baseline (1736.535 us; speedup 1.0000x reference)
//
#include <hip/hip_runtime.h>
#include <hip/hip_bf16.h>

#define N_NODES 100000
#define N_EDGES 3200000
#define NFEAT 256
#define NHID 128
#define NCLASS 64
#define SCAN_B 1024
#define NB_SCAN ((N_NODES + SCAN_B - 1) / SCAN_B)   // 98

// ---------------- degree count ----------------
__global__ void k_deg(const int* __restrict__ src, const int* __restrict__ dst,
                      int* __restrict__ deg_out, int* __restrict__ deg_in) {
    int e = blockIdx.x * blockDim.x + threadIdx.x;
    if (e < N_EDGES) {
        atomicAdd(&deg_out[src[e]], 1);
        atomicAdd(&deg_in[dst[e]], 1);
    }
}

// ---------------- norms ----------------
__global__ void k_norm(const int* __restrict__ deg_out, const int* __restrict__ deg_in,
                       float* __restrict__ n_src, float* __restrict__ n_dst) {
    int i = blockIdx.x * blockDim.x + threadIdx.x;
    if (i < N_NODES) {
        int dot = deg_out[i]; if (dot < 1) dot = 1;
        int din = deg_in[i];  if (din < 1) din = 1;
        n_src[i] = rsqrtf((float)dot);
        n_dst[i] = rsqrtf((float)din);
    }
}

// ---------------- scan (3-pass) ----------------
__global__ void k_scan1(const int* __restrict__ deg_in, int* __restrict__ row_ptr,
                        int* __restrict__ blk_sums) {
    __shared__ int sh[SCAN_B];
    int i = blockIdx.x * SCAN_B + threadIdx.x;
    int v = (i < N_NODES) ? deg_in[i] : 0;
    sh[threadIdx.x] = v;
    __syncthreads();
    for (int o = 1; o < SCAN_B; o <<= 1) {
        int t = 0;
        if ((int)threadIdx.x >= o) t = sh[threadIdx.x - o];
        __syncthreads();
        sh[threadIdx.x] += t;
        __syncthreads();
    }
    if (i < N_NODES) row_ptr[i] = sh[threadIdx.x] - v;   // exclusive within block
    if (threadIdx.x == SCAN_B - 1) blk_sums[blockIdx.x] = sh[SCAN_B - 1];
}

__global__ void k_scan2(int* __restrict__ blk_sums) {
    if (threadIdx.x == 0 && blockIdx.x == 0) {
        int acc = 0;
        for (int b = 0; b < NB_SCAN; b++) { int v = blk_sums[b]; blk_sums[b] = acc; acc += v; }
        blk_sums[NB_SCAN] = acc;   // total (== N_EDGES)
    }
}

__global__ void k_scan3(const int* __restrict__ blk_sums, int* __restrict__ row_ptr,
                        int* __restrict__ cursor) {
    int i = blockIdx.x * SCAN_B + threadIdx.x;
    if (i < N_NODES) {
        int v = row_ptr[i] + blk_sums[blockIdx.x];
        row_ptr[i] = v;
        cursor[i] = v;
    }
    if (i == 0) row_ptr[N_NODES] = blk_sums[NB_SCAN];
}

// ---------------- counting-sort fill: CSR by dst ----------------
__global__ void k_fill(const int* __restrict__ src, const int* __restrict__ dst,
                       int* __restrict__ cursor, int* __restrict__ col) {
    int e = blockIdx.x * blockDim.x + threadIdx.x;
    if (e < N_EDGES) {
        int slot = atomicAdd(&cursor[dst[e]], 1);
        col[slot] = src[e];
    }
}

// ---------------- tiny weight-collapse GEMMs ----------------
// W01[r,c] = sum_k W0[r,k] * W1[k,c];  r<256, c<128
__global__ void k_w01(const float* __restrict__ W0, const float* __restrict__ W1,
                      float* __restrict__ W01) {
    __shared__ float row[NHID];
    int r = blockIdx.x, c = threadIdx.x;   // 128 threads
    row[c] = W0[r * NHID + c];
    __syncthreads();
    float acc = 0.f;
    for (int k = 0; k < NHID; k++) acc += row[k] * W1[k * NHID + c];
    W01[r * NHID + c] = acc;
}

// Wc[r,c] = sum_k W01[r,k] * W2[k,c];  r<256, c<64
__global__ void k_wc(const float* __restrict__ W01, const float* __restrict__ W2,
                     float* __restrict__ Wc) {
    __shared__ float row[NHID];
    int r = blockIdx.x, c = threadIdx.x;   // 64 threads
    row[c] = W01[r * NHID + c];
    row[c + 64] = W01[r * NHID + c + 64];
    __syncthreads();
    float acc = 0.f;
    for (int k = 0; k < NHID; k++) acc += row[k] * W2[k * NCLASS + c];
    Wc[r * NCLASS + c] = acc;
}

// bv[0..63] = b0@W1@W2, bv[64..127] = b1@W2
__global__ void k_bv(const float* __restrict__ b0, const float* __restrict__ W1,
                     const float* __restrict__ b1, const float* __restrict__ W2,
                     float* __restrict__ bv) {
    __shared__ float tmp[NHID];
    int c = threadIdx.x;   // 64 threads
    for (int cc = c; cc < NHID; cc += 64) {
        float a = 0.f;
        for (int k = 0; k < NHID; k++) a += b0[k] * W1[k * NHID + cc];
        tmp[cc] = a;
    }
    __syncthreads();
    float a1 = 0.f, a2 = 0.f;
    for (int k = 0; k < NHID; k++) {
        float w = W2[k * NCLASS + c];
        a1 += tmp[k] * w;
        a2 += b1[k] * w;
    }
    bv[c] = a1;
    bv[64 + c] = a2;
}

// ---------------- main GEMM: y = x @ Wc  [N,256]x[256,64] ----------------
// 256 threads = 4 waves; each wave owns 2 rows (wid, wid+4); lane = output col.
__global__ void k_gemm_y(const float* __restrict__ x, const float* __restrict__ Wc,
                         float* __restrict__ y) {
    __shared__ float wc_sh[128 * NCLASS];   // 32 KB, staged in 2 halves of K
    __shared__ float x_sh[8][NFEAT];        // 8 KB
    int tid = threadIdx.x;
    int row0 = blockIdx.x * 8;
    for (int i = tid; i < 8 * NFEAT; i += 256) {
        int r = i >> 8, k = i & 255;
        int gr = row0 + r;
        x_sh[r][k] = (gr < N_NODES) ? x[gr * NFEAT + k] : 0.f;
    }
    int wid = tid >> 6, lane = tid & 63;
    float acc1 = 0.f, acc2 = 0.f;
    for (int half = 0; half < 2; half++) {
        __syncthreads();
        for (int i = tid; i < 128 * NCLASS; i += 256) wc_sh[i] = Wc[half * 128 * NCLASS + i];
        __syncthreads();
        const float* xr1 = &x_sh[wid][half * 128];
        const float* xr2 = &x_sh[wid + 4][half * 128];
#pragma unroll 4
        for (int k = 0; k < 128; k++) {
            float w = wc_sh[k * NCLASS + lane];
            acc1 += xr1[k] * w;
            acc2 += xr2[k] * w;
        }
    }
    int g1 = row0 + wid, g2 = row0 + wid + 4;
    if (g1 < N_NODES) y[g1 * NCLASS + lane] = acc1;
    if (g2 < N_NODES) y[g2 * NCLASS + lane] = acc2;
}

// ---------------- aggregation over 64 features: out = n_dst * (A . (n_src*in)) ----------------
// 4 waves/block, one node per wave, lane = feature.
__global__ void k_agg64(const int* __restrict__ row_ptr, const int* __restrict__ col,
                        const float* __restrict__ n_src, const float* __restrict__ n_dst,
                        const float* __restrict__ in, float* __restrict__ out) {
    int wid = threadIdx.x >> 6, lane = threadIdx.x & 63;
    int node = blockIdx.x * 4 + wid;
    if (node >= N_NODES) return;
    int s = row_ptr[node], e = row_ptr[node + 1];
    float acc = 0.f;
    for (int p = s; p < e; p++) {
        int j = col[p];
        acc += n_src[j] * in[j * NCLASS + lane];
    }
    out[node * NCLASS + lane] = acc * n_dst[node];
}

// ---------------- scalar aggregation: out[i] = n_dst[i] * sum_j n_src[j]*(in?in[j]:1) ----------------
__global__ void k_aggs(const int* __restrict__ row_ptr, const int* __restrict__ col,
                       const float* __restrict__ n_src, const float* __restrict__ n_dst,
                       const float* __restrict__ in, float* __restrict__ out) {
    int wid = threadIdx.x >> 6, lane = threadIdx.x & 63;
    int node = blockIdx.x * 4 + wid;
    if (node >= N_NODES) return;
    int s = row_ptr[node], e = row_ptr[node + 1];
    float acc = 0.f;
    for (int p = s + lane; p < e; p += 64) {
        int j = col[p];
        float v = n_src[j];
        if (in) v *= in[j];
        acc += v;
    }
    for (int m = 32; m >= 1; m >>= 1) acc += __shfl_xor(acc, m, 64);
    if (lane == 0) out[node] = acc * n_dst[node];
}

// ---------------- bias + softmax epilogue ----------------
// Reads z from zin, writes f32 probs to out (distinct buffers).
__global__ void k_final(const float* __restrict__ zin, const float* __restrict__ t1,
                        const float* __restrict__ t2, const float* __restrict__ bv,
                        const float* __restrict__ b2, float* __restrict__ out) {
    int wid = threadIdx.x >> 6, lane = threadIdx.x & 63;
    int node = blockIdx.x * 4 + wid;
    if (node >= N_NODES) return;
    float v = zin[node * NCLASS + lane] + t2[node] * bv[lane] + t1[node] * bv[64 + lane] + b2[lane];
    float m = v;
    for (int s = 32; s >= 1; s >>= 1) m = fmaxf(m, __shfl_xor(m, s, 64));
    float ex = __expf(v - m);
    float sum = ex;
    for (int s = 32; s >= 1; s >>= 1) sum += __shfl_xor(sum, s, 64);
    out[node * NCLASS + lane] = ex / sum;
}

extern "C" void kernel_launch(void* const* d_in, const int* in_sizes, int n_in,
                              void* d_out, int out_size, void* d_ws, size_t ws_size,
                              hipStream_t stream) {
    const float* x   = (const float*)d_in[0];
    const int*   src = (const int*)d_in[1];
    const int*   dst = (const int*)d_in[2];
    const float* W0  = (const float*)d_in[3];
    const float* b0  = (const float*)d_in[4];
    const float* W1  = (const float*)d_in[5];
    const float* b1  = (const float*)d_in[6];
    const float* W2  = (const float*)d_in[7];
    const float* b2  = (const float*)d_in[8];
    float* out = (float*)d_out;

    // workspace carve-up (~41.4 MB)
    size_t off = 0;
    auto alloc = [&](size_t bytes) {
        void* p = (char*)d_ws + off;
        off = (off + bytes + 255) & ~(size_t)255;
        return p;
    };
    int*   deg_out  = (int*)alloc(N_NODES * 4);
    int*   deg_in   = (int*)alloc(N_NODES * 4);
    float* n_src    = (float*)alloc(N_NODES * 4);
    float* n_dst    = (float*)alloc(N_NODES * 4);
    int*   row_ptr  = (int*)alloc((N_NODES + 1) * 4);
    int*   cursor   = (int*)alloc(N_NODES * 4);
    int*   blk_sums = (int*)alloc((NB_SCAN + 1) * 4);
    int*   col      = (int*)alloc((size_t)N_EDGES * 4);
    float* W01      = (float*)alloc(NFEAT * NHID * 4);
    float* Wc       = (float*)alloc(NFEAT * NCLASS * 4);
    float* bv       = (float*)alloc(128 * 4);
    float* t1       = (float*)alloc(N_NODES * 4);
    float* t2       = (float*)alloc(N_NODES * 4);
    float* bufA     = (float*)alloc((size_t)N_NODES * NCLASS * 4);
    (void)ws_size; (void)in_sizes; (void)n_in; (void)out_size;

    hipMemsetAsync(deg_out, 0, N_NODES * 4, stream);
    hipMemsetAsync(deg_in, 0, N_NODES * 4, stream);

    const int TB = 256;
    const int EB = (N_EDGES + TB - 1) / TB;
    const int NBn = (N_NODES + TB - 1) / TB;
    const int NW = (N_NODES + 3) / 4;   // wave-per-node kernels

    k_deg<<<EB, TB, 0, stream>>>(src, dst, deg_out, deg_in);
    k_norm<<<NBn, TB, 0, stream>>>(deg_out, deg_in, n_src, n_dst);
    k_scan1<<<NB_SCAN, SCAN_B, 0, stream>>>(deg_in, row_ptr, blk_sums);
    k_scan2<<<1, 64, 0, stream>>>(blk_sums);
    k_scan3<<<NB_SCAN, SCAN_B, 0, stream>>>(blk_sums, row_ptr, cursor);
    k_fill<<<EB, TB, 0, stream>>>(src, dst, cursor, col);

    k_w01<<<NFEAT, NHID, 0, stream>>>(W0, W1, W01);
    k_wc<<<NFEAT, NCLASS, 0, stream>>>(W01, W2, Wc);
    k_bv<<<1, NCLASS, 0, stream>>>(b0, W1, b1, W2, bv);

    // Ping-pong the [N,64] feature maps between d_out (f32 scratch until the end) and bufA.
    k_gemm_y<<<(N_NODES + 7) / 8, 256, 0, stream>>>(x, Wc, out);          // Y -> OUT

    k_aggs<<<NW, 256, 0, stream>>>(row_ptr, col, n_src, n_dst, (const float*)nullptr, t1);
    k_aggs<<<NW, 256, 0, stream>>>(row_ptr, col, n_src, n_dst, t1, t2);

    k_agg64<<<NW, 256, 0, stream>>>(row_ptr, col, n_src, n_dst, out, bufA);   // Z1 -> bufA
    k_agg64<<<NW, 256, 0, stream>>>(row_ptr, col, n_src, n_dst, bufA, out);   // Z2 -> OUT
    k_agg64<<<NW, 256, 0, stream>>>(row_ptr, col, n_src, n_dst, out, bufA);   // Z3 -> bufA

    k_final<<<NW, 256, 0, stream>>>(bufA, t1, t2, bv, b2, out);
}

// Round 3
// 1223.905 us; speedup vs baseline: 1.4188x; 1.4188x over previous
//
#include <hip/hip_runtime.h>
#include <hip/hip_bf16.h>

#define N_NODES 100000
#define N_EDGES 3200000
#define NFEAT 256
#define NHID 128
#define NCLASS 64
#define SCAN_B 1024
#define NB_SCAN ((N_NODES + SCAN_B - 1) / SCAN_B)   // 98

// ---------------- degree count (4 edges/thread, int4 loads) ----------------
__global__ void k_deg(const int4* __restrict__ src4, const int4* __restrict__ dst4,
                      int* __restrict__ deg_out, int* __restrict__ deg_in) {
    int t = blockIdx.x * blockDim.x + threadIdx.x;
    if (t < N_EDGES / 4) {
        int4 s = src4[t], d = dst4[t];
        atomicAdd(&deg_out[s.x], 1);
        atomicAdd(&deg_out[s.y], 1);
        atomicAdd(&deg_out[s.z], 1);
        atomicAdd(&deg_out[s.w], 1);
        atomicAdd(&deg_in[d.x], 1);
        atomicAdd(&deg_in[d.y], 1);
        atomicAdd(&deg_in[d.z], 1);
        atomicAdd(&deg_in[d.w], 1);
    }
}

// ---------------- norms ----------------
__global__ void k_norm(const int* __restrict__ deg_out, const int* __restrict__ deg_in,
                       float* __restrict__ n_src, float* __restrict__ n_dst) {
    int i = blockIdx.x * blockDim.x + threadIdx.x;
    if (i < N_NODES) {
        int dot = deg_out[i]; if (dot < 1) dot = 1;
        int din = deg_in[i];  if (din < 1) din = 1;
        n_src[i] = rsqrtf((float)dot);
        n_dst[i] = rsqrtf((float)din);
    }
}

// ---------------- scan (3-pass) ----------------
__global__ void k_scan1(const int* __restrict__ deg_in, int* __restrict__ row_ptr,
                        int* __restrict__ blk_sums) {
    __shared__ int sh[SCAN_B];
    int i = blockIdx.x * SCAN_B + threadIdx.x;
    int v = (i < N_NODES) ? deg_in[i] : 0;
    sh[threadIdx.x] = v;
    __syncthreads();
    for (int o = 1; o < SCAN_B; o <<= 1) {
        int t = 0;
        if ((int)threadIdx.x >= o) t = sh[threadIdx.x - o];
        __syncthreads();
        sh[threadIdx.x] += t;
        __syncthreads();
    }
    if (i < N_NODES) row_ptr[i] = sh[threadIdx.x] - v;   // exclusive within block
    if (threadIdx.x == SCAN_B - 1) blk_sums[blockIdx.x] = sh[SCAN_B - 1];
}

__global__ void k_scan2(int* __restrict__ blk_sums) {
    if (threadIdx.x == 0 && blockIdx.x == 0) {
        int acc = 0;
        for (int b = 0; b < NB_SCAN; b++) { int v = blk_sums[b]; blk_sums[b] = acc; acc += v; }
        blk_sums[NB_SCAN] = acc;
    }
}

__global__ void k_scan3(const int* __restrict__ blk_sums, int* __restrict__ row_ptr,
                        int* __restrict__ cursor) {
    int i = blockIdx.x * SCAN_B + threadIdx.x;
    if (i < N_NODES) {
        int v = row_ptr[i] + blk_sums[blockIdx.x];
        row_ptr[i] = v;
        cursor[i] = v;
    }
    if (i == 0) row_ptr[N_NODES] = blk_sums[NB_SCAN];
}

// ---------------- counting-sort fill: CSR by dst (4 edges/thread) ----------------
__global__ void k_fill(const int4* __restrict__ src4, const int4* __restrict__ dst4,
                       int* __restrict__ cursor, int* __restrict__ col) {
    int t = blockIdx.x * blockDim.x + threadIdx.x;
    if (t < N_EDGES / 4) {
        int4 s = src4[t], d = dst4[t];
        int p0 = atomicAdd(&cursor[d.x], 1);
        int p1 = atomicAdd(&cursor[d.y], 1);
        int p2 = atomicAdd(&cursor[d.z], 1);
        int p3 = atomicAdd(&cursor[d.w], 1);
        col[p0] = s.x;
        col[p1] = s.y;
        col[p2] = s.z;
        col[p3] = s.w;
    }
}

// ---------------- tiny weight-collapse GEMMs ----------------
__global__ void k_w01(const float* __restrict__ W0, const float* __restrict__ W1,
                      float* __restrict__ W01) {
    __shared__ float row[NHID];
    int r = blockIdx.x, c = threadIdx.x;   // 128 threads
    row[c] = W0[r * NHID + c];
    __syncthreads();
    float acc = 0.f;
    for (int k = 0; k < NHID; k++) acc += row[k] * W1[k * NHID + c];
    W01[r * NHID + c] = acc;
}

__global__ void k_wc(const float* __restrict__ W01, const float* __restrict__ W2,
                     float* __restrict__ Wc) {
    __shared__ float row[NHID];
    int r = blockIdx.x, c = threadIdx.x;   // 64 threads
    row[c] = W01[r * NHID + c];
    row[c + 64] = W01[r * NHID + c + 64];
    __syncthreads();
    float acc = 0.f;
    for (int k = 0; k < NHID; k++) acc += row[k] * W2[k * NCLASS + c];
    Wc[r * NCLASS + c] = acc;
}

// bv[0..63] = b0@W1@W2, bv[64..127] = b1@W2
__global__ void k_bv(const float* __restrict__ b0, const float* __restrict__ W1,
                     const float* __restrict__ b1, const float* __restrict__ W2,
                     float* __restrict__ bv) {
    __shared__ float tmp[NHID];
    int c = threadIdx.x;   // 64 threads
    for (int cc = c; cc < NHID; cc += 64) {
        float a = 0.f;
        for (int k = 0; k < NHID; k++) a += b0[k] * W1[k * NHID + cc];
        tmp[cc] = a;
    }
    __syncthreads();
    float a1 = 0.f, a2 = 0.f;
    for (int k = 0; k < NHID; k++) {
        float w = W2[k * NCLASS + c];
        a1 += tmp[k] * w;
        a2 += b1[k] * w;
    }
    bv[c] = a1;
    bv[64 + c] = a2;
}

// ---------------- main GEMM: y = x @ Wc  [N,256]x[256,64] ----------------
__global__ void k_gemm_y(const float* __restrict__ x, const float* __restrict__ Wc,
                         float* __restrict__ y) {
    __shared__ float wc_sh[128 * NCLASS];   // 32 KB, staged in 2 halves of K
    __shared__ float x_sh[8][NFEAT];        // 8 KB
    int tid = threadIdx.x;
    int row0 = blockIdx.x * 8;
    for (int i = tid; i < 8 * NFEAT; i += 256) {
        int r = i >> 8, k = i & 255;
        int gr = row0 + r;
        x_sh[r][k] = (gr < N_NODES) ? x[gr * NFEAT + k] : 0.f;
    }
    int wid = tid >> 6, lane = tid & 63;
    float acc1 = 0.f, acc2 = 0.f;
    for (int half = 0; half < 2; half++) {
        __syncthreads();
        for (int i = tid; i < 128 * NCLASS; i += 256) wc_sh[i] = Wc[half * 128 * NCLASS + i];
        __syncthreads();
        const float* xr1 = &x_sh[wid][half * 128];
        const float* xr2 = &x_sh[wid + 4][half * 128];
#pragma unroll 4
        for (int k = 0; k < 128; k++) {
            float w = wc_sh[k * NCLASS + lane];
            acc1 += xr1[k] * w;
            acc2 += xr2[k] * w;
        }
    }
    int g1 = row0 + wid, g2 = row0 + wid + 4;
    if (g1 < N_NODES) y[g1 * NCLASS + lane] = acc1;
    if (g2 < N_NODES) y[g2 * NCLASS + lane] = acc2;
}

// ---------------- fused aggregation passes ----------------
// One node per wave, lane = feature. Unrolled x4 for outstanding gathers.
// PASS 1: out = Âin (feature), tout = Â·1       (scalar, free: reuses n_src loads)
// PASS 2: out = Âin (feature), tout = Â·tin     (one extra 4B broadcast gather)
// PASS 3: out = softmax(Âin + t2*bv0 + t1*bv1 + b2)   (fused epilogue)
template <int PASS>
__global__ __launch_bounds__(256) void k_agg(
        const int* __restrict__ row_ptr, const int* __restrict__ col,
        const float* __restrict__ n_src, const float* __restrict__ n_dst,
        const float* __restrict__ in, float* __restrict__ out,
        const float* __restrict__ tin, float* __restrict__ tout,
        const float* __restrict__ t1, const float* __restrict__ t2,
        const float* __restrict__ bv, const float* __restrict__ b2) {
    int wid = threadIdx.x >> 6, lane = threadIdx.x & 63;
    int node = blockIdx.x * 4 + wid;
    if (node >= N_NODES) return;
    int s = row_ptr[node], e = row_ptr[node + 1];
    float acc = 0.f, accs = 0.f;
    int p = s;
    for (; p + 4 <= e; p += 4) {
        int j0 = col[p], j1 = col[p + 1], j2 = col[p + 2], j3 = col[p + 3];
        float ns0 = n_src[j0], ns1 = n_src[j1], ns2 = n_src[j2], ns3 = n_src[j3];
        float v0 = in[(size_t)j0 * NCLASS + lane];
        float v1 = in[(size_t)j1 * NCLASS + lane];
        float v2 = in[(size_t)j2 * NCLASS + lane];
        float v3 = in[(size_t)j3 * NCLASS + lane];
        acc += ns0 * v0 + ns1 * v1 + ns2 * v2 + ns3 * v3;
        if (PASS == 1) accs += ns0 + ns1 + ns2 + ns3;
        if (PASS == 2) accs += ns0 * tin[j0] + ns1 * tin[j1] + ns2 * tin[j2] + ns3 * tin[j3];
    }
    for (; p < e; p++) {
        int j = col[p];
        float ns = n_src[j];
        acc += ns * in[(size_t)j * NCLASS + lane];
        if (PASS == 1) accs += ns;
        if (PASS == 2) accs += ns * tin[j];
    }
    float nd = n_dst[node];
    if (PASS == 3) {
        float v = acc * nd + t2[node] * bv[lane] + t1[node] * bv[64 + lane] + b2[lane];
        float m = v;
        for (int o = 32; o >= 1; o >>= 1) m = fmaxf(m, __shfl_xor(m, o, 64));
        float ex = __expf(v - m);
        float sum = ex;
        for (int o = 32; o >= 1; o >>= 1) sum += __shfl_xor(sum, o, 64);
        out[(size_t)node * NCLASS + lane] = ex / sum;
    } else {
        out[(size_t)node * NCLASS + lane] = acc * nd;
        if (lane == 0) tout[node] = accs * nd;
    }
}

extern "C" void kernel_launch(void* const* d_in, const int* in_sizes, int n_in,
                              void* d_out, int out_size, void* d_ws, size_t ws_size,
                              hipStream_t stream) {
    const float* x   = (const float*)d_in[0];
    const int*   src = (const int*)d_in[1];
    const int*   dst = (const int*)d_in[2];
    const float* W0  = (const float*)d_in[3];
    const float* b0  = (const float*)d_in[4];
    const float* W1  = (const float*)d_in[5];
    const float* b1  = (const float*)d_in[6];
    const float* W2  = (const float*)d_in[7];
    const float* b2  = (const float*)d_in[8];
    float* out = (float*)d_out;

    size_t off = 0;
    auto alloc = [&](size_t bytes) {
        void* p = (char*)d_ws + off;
        off = (off + bytes + 255) & ~(size_t)255;
        return p;
    };
    int*   deg_out  = (int*)alloc(N_NODES * 4);
    int*   deg_in   = (int*)alloc(N_NODES * 4);
    float* n_src    = (float*)alloc(N_NODES * 4);
    float* n_dst    = (float*)alloc(N_NODES * 4);
    int*   row_ptr  = (int*)alloc((N_NODES + 1) * 4);
    int*   cursor   = (int*)alloc(N_NODES * 4);
    int*   blk_sums = (int*)alloc((NB_SCAN + 1) * 4);
    int*   col      = (int*)alloc((size_t)N_EDGES * 4);
    float* W01      = (float*)alloc(NFEAT * NHID * 4);
    float* Wc       = (float*)alloc(NFEAT * NCLASS * 4);
    float* bv       = (float*)alloc(128 * 4);
    float* t1       = (float*)alloc(N_NODES * 4);
    float* t2       = (float*)alloc(N_NODES * 4);
    float* bufA     = (float*)alloc((size_t)N_NODES * NCLASS * 4);
    (void)ws_size; (void)in_sizes; (void)n_in; (void)out_size;

    hipMemsetAsync(deg_out, 0, N_NODES * 4, stream);
    hipMemsetAsync(deg_in, 0, N_NODES * 4, stream);

    const int TB = 256;
    const int EB4 = (N_EDGES / 4 + TB - 1) / TB;
    const int NBn = (N_NODES + TB - 1) / TB;
    const int NW = (N_NODES + 3) / 4;   // wave-per-node kernels

    k_deg<<<EB4, TB, 0, stream>>>((const int4*)src, (const int4*)dst, deg_out, deg_in);
    k_norm<<<NBn, TB, 0, stream>>>(deg_out, deg_in, n_src, n_dst);
    k_scan1<<<NB_SCAN, SCAN_B, 0, stream>>>(deg_in, row_ptr, blk_sums);
    k_scan2<<<1, 64, 0, stream>>>(blk_sums);
    k_scan3<<<NB_SCAN, SCAN_B, 0, stream>>>(blk_sums, row_ptr, cursor);
    k_fill<<<EB4, TB, 0, stream>>>((const int4*)src, (const int4*)dst, cursor, col);

    k_w01<<<NFEAT, NHID, 0, stream>>>(W0, W1, W01);
    k_wc<<<NFEAT, NCLASS, 0, stream>>>(W01, W2, Wc);
    k_bv<<<1, NCLASS, 0, stream>>>(b0, W1, b1, W2, bv);

    // Y -> bufA; Z1 -> OUT (+t1); Z2 -> bufA (+t2); pass3: bufA -> softmax -> OUT
    k_gemm_y<<<(N_NODES + 7) / 8, 256, 0, stream>>>(x, Wc, bufA);

    k_agg<1><<<NW, 256, 0, stream>>>(row_ptr, col, n_src, n_dst, bufA, out,
                                     nullptr, t1, nullptr, nullptr, nullptr, nullptr);
    k_agg<2><<<NW, 256, 0, stream>>>(row_ptr, col, n_src, n_dst, out, bufA,
                                     t1, t2, nullptr, nullptr, nullptr, nullptr);
    k_agg<3><<<NW, 256, 0, stream>>>(row_ptr, col, n_src, n_dst, bufA, out,
                                     nullptr, nullptr, t1, t2, bv, b2);
}

// Round 4
// 1107.004 us; speedup vs baseline: 1.5687x; 1.1056x over previous
//
#include <hip/hip_runtime.h>
#include <hip/hip_bf16.h>

#define N_NODES 100000
#define N_EDGES 3200000
#define NFEAT 256
#define NHID 128
#define NCLASS 64
#define SCAN_B 1024
#define NB_SCAN ((N_NODES + SCAN_B - 1) / SCAN_B)   // 98
#define NVEC4 (N_EDGES / 4)                          // 800000
#define NODE_RANGE (N_NODES / 8)                     // 12500
#define NSLICE 128                                   // slices per XCD group

// ---------------- XCD-partitioned degree count ----------------
// blocks with blockIdx%8==g own node range [g*12500,(g+1)*12500): atomics on
// deg_out/deg_in lines stay XCD-local (blockIdx%8 ~ XCD round-robin heuristic;
// correctness does not depend on the mapping).
__global__ __launch_bounds__(256) void k_deg(const int4* __restrict__ src4,
                                             const int4* __restrict__ dst4,
                                             int* __restrict__ deg_out,
                                             int* __restrict__ deg_in) {
    int g = blockIdx.x & 7;
    int slice = blockIdx.x >> 3;
    int lo = g * NODE_RANGE, hi = lo + NODE_RANGE;
    for (int t = slice * 256 + threadIdx.x; t < NVEC4; t += NSLICE * 256) {
        int4 s = src4[t], d = dst4[t];
        if (s.x >= lo && s.x < hi) atomicAdd(&deg_out[s.x], 1);
        if (s.y >= lo && s.y < hi) atomicAdd(&deg_out[s.y], 1);
        if (s.z >= lo && s.z < hi) atomicAdd(&deg_out[s.z], 1);
        if (s.w >= lo && s.w < hi) atomicAdd(&deg_out[s.w], 1);
        if (d.x >= lo && d.x < hi) atomicAdd(&deg_in[d.x], 1);
        if (d.y >= lo && d.y < hi) atomicAdd(&deg_in[d.y], 1);
        if (d.z >= lo && d.z < hi) atomicAdd(&deg_in[d.z], 1);
        if (d.w >= lo && d.w < hi) atomicAdd(&deg_in[d.w], 1);
    }
}

// ---------------- norms ----------------
__global__ void k_norm(const int* __restrict__ deg_out, const int* __restrict__ deg_in,
                       float* __restrict__ n_src, float* __restrict__ n_dst) {
    int i = blockIdx.x * blockDim.x + threadIdx.x;
    if (i < N_NODES) {
        int dot = deg_out[i]; if (dot < 1) dot = 1;
        int din = deg_in[i];  if (din < 1) din = 1;
        n_src[i] = rsqrtf((float)dot);
        n_dst[i] = rsqrtf((float)din);
    }
}

// ---------------- scan (3-pass) ----------------
__global__ void k_scan1(const int* __restrict__ deg_in, int* __restrict__ row_ptr,
                        int* __restrict__ blk_sums) {
    __shared__ int sh[SCAN_B];
    int i = blockIdx.x * SCAN_B + threadIdx.x;
    int v = (i < N_NODES) ? deg_in[i] : 0;
    sh[threadIdx.x] = v;
    __syncthreads();
    for (int o = 1; o < SCAN_B; o <<= 1) {
        int t = 0;
        if ((int)threadIdx.x >= o) t = sh[threadIdx.x - o];
        __syncthreads();
        sh[threadIdx.x] += t;
        __syncthreads();
    }
    if (i < N_NODES) row_ptr[i] = sh[threadIdx.x] - v;   // exclusive within block
    if (threadIdx.x == SCAN_B - 1) blk_sums[blockIdx.x] = sh[SCAN_B - 1];
}

__global__ void k_scan2(int* __restrict__ blk_sums) {
    if (threadIdx.x == 0 && blockIdx.x == 0) {
        int acc = 0;
        for (int b = 0; b < NB_SCAN; b++) { int v = blk_sums[b]; blk_sums[b] = acc; acc += v; }
        blk_sums[NB_SCAN] = acc;
    }
}

__global__ void k_scan3(const int* __restrict__ blk_sums, int* __restrict__ row_ptr,
                        int* __restrict__ cursor) {
    int i = blockIdx.x * SCAN_B + threadIdx.x;
    if (i < N_NODES) {
        int v = row_ptr[i] + blk_sums[blockIdx.x];
        row_ptr[i] = v;
        cursor[i] = v;
    }
    if (i == 0) row_ptr[N_NODES] = blk_sums[NB_SCAN];
}

// ---------------- XCD-partitioned counting-sort fill ----------------
// Same partition trick: cursor atomics AND col scatter-writes stay XCD-local.
__global__ __launch_bounds__(256) void k_fill(const int4* __restrict__ src4,
                                              const int4* __restrict__ dst4,
                                              int* __restrict__ cursor,
                                              int* __restrict__ col) {
    int g = blockIdx.x & 7;
    int slice = blockIdx.x >> 3;
    int lo = g * NODE_RANGE, hi = lo + NODE_RANGE;
    for (int t = slice * 256 + threadIdx.x; t < NVEC4; t += NSLICE * 256) {
        int4 s = src4[t], d = dst4[t];
        if (d.x >= lo && d.x < hi) { int p = atomicAdd(&cursor[d.x], 1); col[p] = s.x; }
        if (d.y >= lo && d.y < hi) { int p = atomicAdd(&cursor[d.y], 1); col[p] = s.y; }
        if (d.z >= lo && d.z < hi) { int p = atomicAdd(&cursor[d.z], 1); col[p] = s.z; }
        if (d.w >= lo && d.w < hi) { int p = atomicAdd(&cursor[d.w], 1); col[p] = s.w; }
    }
}

// ---------------- tiny weight-collapse GEMMs ----------------
__global__ void k_w01(const float* __restrict__ W0, const float* __restrict__ W1,
                      float* __restrict__ W01) {
    __shared__ float row[NHID];
    int r = blockIdx.x, c = threadIdx.x;   // 128 threads
    row[c] = W0[r * NHID + c];
    __syncthreads();
    float acc = 0.f;
    for (int k = 0; k < NHID; k++) acc += row[k] * W1[k * NHID + c];
    W01[r * NHID + c] = acc;
}

__global__ void k_wc(const float* __restrict__ W01, const float* __restrict__ W2,
                     float* __restrict__ Wc) {
    __shared__ float row[NHID];
    int r = blockIdx.x, c = threadIdx.x;   // 64 threads
    row[c] = W01[r * NHID + c];
    row[c + 64] = W01[r * NHID + c + 64];
    __syncthreads();
    float acc = 0.f;
    for (int k = 0; k < NHID; k++) acc += row[k] * W2[k * NCLASS + c];
    Wc[r * NCLASS + c] = acc;
}

// bv[0..63] = b0@W1@W2, bv[64..127] = b1@W2
__global__ void k_bv(const float* __restrict__ b0, const float* __restrict__ W1,
                     const float* __restrict__ b1, const float* __restrict__ W2,
                     float* __restrict__ bv) {
    __shared__ float tmp[NHID];
    int c = threadIdx.x;   // 64 threads
    for (int cc = c; cc < NHID; cc += 64) {
        float a = 0.f;
        for (int k = 0; k < NHID; k++) a += b0[k] * W1[k * NHID + cc];
        tmp[cc] = a;
    }
    __syncthreads();
    float a1 = 0.f, a2 = 0.f;
    for (int k = 0; k < NHID; k++) {
        float w = W2[k * NCLASS + c];
        a1 += tmp[k] * w;
        a2 += b1[k] * w;
    }
    bv[c] = a1;
    bv[64 + c] = a2;
}

// ---------------- main GEMM: y = x @ Wc  [N,256]x[256,64] ----------------
__global__ void k_gemm_y(const float* __restrict__ x, const float* __restrict__ Wc,
                         float* __restrict__ y) {
    __shared__ float wc_sh[128 * NCLASS];   // 32 KB, staged in 2 halves of K
    __shared__ float x_sh[8][NFEAT];        // 8 KB
    int tid = threadIdx.x;
    int row0 = blockIdx.x * 8;
    for (int i = tid; i < 8 * NFEAT; i += 256) {
        int r = i >> 8, k = i & 255;
        int gr = row0 + r;
        x_sh[r][k] = (gr < N_NODES) ? x[gr * NFEAT + k] : 0.f;
    }
    int wid = tid >> 6, lane = tid & 63;
    float acc1 = 0.f, acc2 = 0.f;
    for (int half = 0; half < 2; half++) {
        __syncthreads();
        for (int i = tid; i < 128 * NCLASS; i += 256) wc_sh[i] = Wc[half * 128 * NCLASS + i];
        __syncthreads();
        const float* xr1 = &x_sh[wid][half * 128];
        const float* xr2 = &x_sh[wid + 4][half * 128];
#pragma unroll 4
        for (int k = 0; k < 128; k++) {
            float w = wc_sh[k * NCLASS + lane];
            acc1 += xr1[k] * w;
            acc2 += xr2[k] * w;
        }
    }
    int g1 = row0 + wid, g2 = row0 + wid + 4;
    if (g1 < N_NODES) y[g1 * NCLASS + lane] = acc1;
    if (g2 < N_NODES) y[g2 * NCLASS + lane] = acc2;
}

// ---------------- fused aggregation passes (unroll x8) ----------------
// One node per wave, lane = feature.
// PASS 1: out = Âin, tout = Â·1 ; PASS 2: out = Âin, tout = Â·tin
// PASS 3: out = softmax(Âin + t2*bv0 + t1*bv1 + b2)
template <int PASS>
__global__ __launch_bounds__(256) void k_agg(
        const int* __restrict__ row_ptr, const int* __restrict__ col,
        const float* __restrict__ n_src, const float* __restrict__ n_dst,
        const float* __restrict__ in, float* __restrict__ out,
        const float* __restrict__ tin, float* __restrict__ tout,
        const float* __restrict__ t1, const float* __restrict__ t2,
        const float* __restrict__ bv, const float* __restrict__ b2) {
    int wid = threadIdx.x >> 6, lane = threadIdx.x & 63;
    int node = blockIdx.x * 4 + wid;
    if (node >= N_NODES) return;
    int s = row_ptr[node], e = row_ptr[node + 1];
    float acc = 0.f, accs = 0.f;
    int p = s;
    for (; p + 8 <= e; p += 8) {
        int j0 = col[p],     j1 = col[p + 1], j2 = col[p + 2], j3 = col[p + 3];
        int j4 = col[p + 4], j5 = col[p + 5], j6 = col[p + 6], j7 = col[p + 7];
        float ns0 = n_src[j0], ns1 = n_src[j1], ns2 = n_src[j2], ns3 = n_src[j3];
        float ns4 = n_src[j4], ns5 = n_src[j5], ns6 = n_src[j6], ns7 = n_src[j7];
        float v0 = in[(size_t)j0 * NCLASS + lane];
        float v1 = in[(size_t)j1 * NCLASS + lane];
        float v2 = in[(size_t)j2 * NCLASS + lane];
        float v3 = in[(size_t)j3 * NCLASS + lane];
        float v4 = in[(size_t)j4 * NCLASS + lane];
        float v5 = in[(size_t)j5 * NCLASS + lane];
        float v6 = in[(size_t)j6 * NCLASS + lane];
        float v7 = in[(size_t)j7 * NCLASS + lane];
        acc += ns0 * v0 + ns1 * v1 + ns2 * v2 + ns3 * v3
             + ns4 * v4 + ns5 * v5 + ns6 * v6 + ns7 * v7;
        if (PASS == 1) accs += ns0 + ns1 + ns2 + ns3 + ns4 + ns5 + ns6 + ns7;
        if (PASS == 2) accs += ns0 * tin[j0] + ns1 * tin[j1] + ns2 * tin[j2] + ns3 * tin[j3]
                             + ns4 * tin[j4] + ns5 * tin[j5] + ns6 * tin[j6] + ns7 * tin[j7];
    }
    for (; p < e; p++) {
        int j = col[p];
        float ns = n_src[j];
        acc += ns * in[(size_t)j * NCLASS + lane];
        if (PASS == 1) accs += ns;
        if (PASS == 2) accs += ns * tin[j];
    }
    float nd = n_dst[node];
    if (PASS == 3) {
        float v = acc * nd + t2[node] * bv[lane] + t1[node] * bv[64 + lane] + b2[lane];
        float m = v;
        for (int o = 32; o >= 1; o >>= 1) m = fmaxf(m, __shfl_xor(m, o, 64));
        float ex = __expf(v - m);
        float sum = ex;
        for (int o = 32; o >= 1; o >>= 1) sum += __shfl_xor(sum, o, 64);
        out[(size_t)node * NCLASS + lane] = ex / sum;
    } else {
        out[(size_t)node * NCLASS + lane] = acc * nd;
        if (lane == 0) tout[node] = accs * nd;
    }
}

extern "C" void kernel_launch(void* const* d_in, const int* in_sizes, int n_in,
                              void* d_out, int out_size, void* d_ws, size_t ws_size,
                              hipStream_t stream) {
    const float* x   = (const float*)d_in[0];
    const int*   src = (const int*)d_in[1];
    const int*   dst = (const int*)d_in[2];
    const float* W0  = (const float*)d_in[3];
    const float* b0  = (const float*)d_in[4];
    const float* W1  = (const float*)d_in[5];
    const float* b1  = (const float*)d_in[6];
    const float* W2  = (const float*)d_in[7];
    const float* b2  = (const float*)d_in[8];
    float* out = (float*)d_out;

    size_t off = 0;
    auto alloc = [&](size_t bytes) {
        void* p = (char*)d_ws + off;
        off = (off + bytes + 255) & ~(size_t)255;
        return p;
    };
    int*   deg_out  = (int*)alloc(N_NODES * 4);
    int*   deg_in   = (int*)alloc(N_NODES * 4);
    float* n_src    = (float*)alloc(N_NODES * 4);
    float* n_dst    = (float*)alloc(N_NODES * 4);
    int*   row_ptr  = (int*)alloc((N_NODES + 1) * 4);
    int*   cursor   = (int*)alloc(N_NODES * 4);
    int*   blk_sums = (int*)alloc((NB_SCAN + 1) * 4);
    int*   col      = (int*)alloc((size_t)N_EDGES * 4);
    float* W01      = (float*)alloc(NFEAT * NHID * 4);
    float* Wc       = (float*)alloc(NFEAT * NCLASS * 4);
    float* bv       = (float*)alloc(128 * 4);
    float* t1       = (float*)alloc(N_NODES * 4);
    float* t2       = (float*)alloc(N_NODES * 4);
    float* bufA     = (float*)alloc((size_t)N_NODES * NCLASS * 4);
    (void)ws_size; (void)in_sizes; (void)n_in; (void)out_size;

    hipMemsetAsync(deg_out, 0, N_NODES * 4, stream);
    hipMemsetAsync(deg_in, 0, N_NODES * 4, stream);

    const int TB = 256;
    const int NBn = (N_NODES + TB - 1) / TB;
    const int NW = (N_NODES + 3) / 4;   // wave-per-node kernels
    const int GP = 8 * NSLICE;          // partitioned edge kernels: 1024 blocks

    k_deg<<<GP, TB, 0, stream>>>((const int4*)src, (const int4*)dst, deg_out, deg_in);
    k_norm<<<NBn, TB, 0, stream>>>(deg_out, deg_in, n_src, n_dst);
    k_scan1<<<NB_SCAN, SCAN_B, 0, stream>>>(deg_in, row_ptr, blk_sums);
    k_scan2<<<1, 64, 0, stream>>>(blk_sums);
    k_scan3<<<NB_SCAN, SCAN_B, 0, stream>>>(blk_sums, row_ptr, cursor);
    k_fill<<<GP, TB, 0, stream>>>((const int4*)src, (const int4*)dst, cursor, col);

    k_w01<<<NFEAT, NHID, 0, stream>>>(W0, W1, W01);
    k_wc<<<NFEAT, NCLASS, 0, stream>>>(W01, W2, Wc);
    k_bv<<<1, NCLASS, 0, stream>>>(b0, W1, b1, W2, bv);

    // Y -> bufA; Z1 -> OUT (+t1); Z2 -> bufA (+t2); pass3: bufA -> softmax -> OUT
    k_gemm_y<<<(N_NODES + 7) / 8, 256, 0, stream>>>(x, Wc, bufA);

    k_agg<1><<<NW, 256, 0, stream>>>(row_ptr, col, n_src, n_dst, bufA, out,
                                     nullptr, t1, nullptr, nullptr, nullptr, nullptr);
    k_agg<2><<<NW, 256, 0, stream>>>(row_ptr, col, n_src, n_dst, out, bufA,
                                     t1, t2, nullptr, nullptr, nullptr, nullptr);
    k_agg<3><<<NW, 256, 0, stream>>>(row_ptr, col, n_src, n_dst, bufA, out,
                                     nullptr, nullptr, t1, t2, bv, b2);
}

// Round 5
// 838.259 us; speedup vs baseline: 2.0716x; 1.3206x over previous
//
#include <hip/hip_runtime.h>
#include <hip/hip_bf16.h>

#define N_NODES 100000
#define N_EDGES 3200000
#define NFEAT 256
#define NHID 128
#define NCLASS 64
#define SCAN_B 1024
#define NB_SCAN ((N_NODES + SCAN_B - 1) / SCAN_B)   // 98
#define NVEC4 (N_EDGES / 4)                          // 800000
#define RANGE (N_NODES / 8)                          // 12500 nodes per group
#define NSL 64                                       // edge slices per group

typedef unsigned int uint32;

// ---------------- phase A: LDS-privatized histogram ----------------
// Block (g = blockIdx&7, sl = blockIdx>>3) owns node range [g*RANGE,(g+1)*RANGE)
// and edge slice sl. Packed u32 counts: src in low 16, dst in high 16.
// No global atomics at all; per-block counts go to scratch[g][sl][RANGE].
__global__ __launch_bounds__(256) void k_hist(const int4* __restrict__ src4,
                                              const int4* __restrict__ dst4,
                                              uint32* __restrict__ scratch) {
    __shared__ uint32 h[RANGE];   // 50 KB
    int g = blockIdx.x & 7, sl = blockIdx.x >> 3;
    int lo = g * RANGE, hi = lo + RANGE;
    for (int i = threadIdx.x; i < RANGE; i += 256) h[i] = 0u;
    __syncthreads();
    for (int t = sl * 256 + threadIdx.x; t < NVEC4; t += NSL * 256) {
        int4 s = src4[t], d = dst4[t];
        if (s.x >= lo && s.x < hi) atomicAdd(&h[s.x - lo], 1u);
        if (s.y >= lo && s.y < hi) atomicAdd(&h[s.y - lo], 1u);
        if (s.z >= lo && s.z < hi) atomicAdd(&h[s.z - lo], 1u);
        if (s.w >= lo && s.w < hi) atomicAdd(&h[s.w - lo], 1u);
        if (d.x >= lo && d.x < hi) atomicAdd(&h[d.x - lo], 65536u);
        if (d.y >= lo && d.y < hi) atomicAdd(&h[d.y - lo], 65536u);
        if (d.z >= lo && d.z < hi) atomicAdd(&h[d.z - lo], 65536u);
        if (d.w >= lo && d.w < hi) atomicAdd(&h[d.w - lo], 65536u);
    }
    __syncthreads();
    uint32* dstp = scratch + ((size_t)(g * NSL + sl)) * RANGE;
    for (int i = threadIdx.x; i < RANGE; i += 256) dstp[i] = h[i];
}

// ---------------- reduce per-block counts -> degrees + norms ----------------
__global__ void k_sumdeg(const uint32* __restrict__ scratch, int* __restrict__ deg_in,
                         float* __restrict__ n_src, float* __restrict__ n_dst) {
    int i = blockIdx.x * blockDim.x + threadIdx.x;
    if (i >= N_NODES) return;
    int g = i / RANGE, r = i - g * RANGE;
    const uint32* base = scratch + (size_t)g * NSL * RANGE + r;
    uint32 so = 0, di = 0;
    for (int s = 0; s < NSL; s++) {
        uint32 v = base[(size_t)s * RANGE];
        so += v & 0xFFFFu;
        di += v >> 16;
    }
    deg_in[i] = (int)di;
    uint32 so1 = so < 1u ? 1u : so;
    uint32 di1 = di < 1u ? 1u : di;
    n_src[i] = rsqrtf((float)so1);
    n_dst[i] = rsqrtf((float)di1);
}

// ---------------- scan (3-pass) over deg_in -> row_ptr ----------------
__global__ void k_scan1(const int* __restrict__ deg_in, int* __restrict__ row_ptr,
                        int* __restrict__ blk_sums) {
    __shared__ int sh[SCAN_B];
    int i = blockIdx.x * SCAN_B + threadIdx.x;
    int v = (i < N_NODES) ? deg_in[i] : 0;
    sh[threadIdx.x] = v;
    __syncthreads();
    for (int o = 1; o < SCAN_B; o <<= 1) {
        int t = 0;
        if ((int)threadIdx.x >= o) t = sh[threadIdx.x - o];
        __syncthreads();
        sh[threadIdx.x] += t;
        __syncthreads();
    }
    if (i < N_NODES) row_ptr[i] = sh[threadIdx.x] - v;   // exclusive within block
    if (threadIdx.x == SCAN_B - 1) blk_sums[blockIdx.x] = sh[SCAN_B - 1];
}

__global__ void k_scan2(int* __restrict__ blk_sums) {
    if (threadIdx.x == 0 && blockIdx.x == 0) {
        int acc = 0;
        for (int b = 0; b < NB_SCAN; b++) { int v = blk_sums[b]; blk_sums[b] = acc; acc += v; }
        blk_sums[NB_SCAN] = acc;
    }
}

__global__ void k_scan3(const int* __restrict__ blk_sums, int* __restrict__ row_ptr) {
    int i = blockIdx.x * SCAN_B + threadIdx.x;
    if (i < N_NODES) row_ptr[i] += blk_sums[blockIdx.x];
    if (i == 0) row_ptr[N_NODES] = blk_sums[NB_SCAN];
}

// ---------------- per-(g,slice) cursor start offsets (in-place on scratch) ----------------
__global__ void k_offsets(uint32* __restrict__ scratch, const int* __restrict__ row_ptr) {
    int i = blockIdx.x * blockDim.x + threadIdx.x;
    if (i >= N_NODES) return;
    int g = i / RANGE, r = i - g * RANGE;
    uint32* base = scratch + (size_t)g * NSL * RANGE + r;
    uint32 run = (uint32)row_ptr[i];
    for (int s = 0; s < NSL; s++) {
        uint32 v = base[(size_t)s * RANGE];
        base[(size_t)s * RANGE] = run;
        run += v >> 16;
    }
}

// ---------------- phase B: atomic-free counting-sort fill ----------------
// Identical (g,sl) decomposition as k_hist; LDS cursors seeded from scratch.
__global__ __launch_bounds__(256) void k_fill2(const int4* __restrict__ src4,
                                               const int4* __restrict__ dst4,
                                               const uint32* __restrict__ scratch,
                                               int* __restrict__ col) {
    __shared__ uint32 cur[RANGE];   // 50 KB
    int g = blockIdx.x & 7, sl = blockIdx.x >> 3;
    int lo = g * RANGE, hi = lo + RANGE;
    const uint32* base = scratch + ((size_t)(g * NSL + sl)) * RANGE;
    for (int i = threadIdx.x; i < RANGE; i += 256) cur[i] = base[i];
    __syncthreads();
    for (int t = sl * 256 + threadIdx.x; t < NVEC4; t += NSL * 256) {
        int4 s = src4[t], d = dst4[t];
        if (d.x >= lo && d.x < hi) { uint32 p = atomicAdd(&cur[d.x - lo], 1u); col[p] = s.x; }
        if (d.y >= lo && d.y < hi) { uint32 p = atomicAdd(&cur[d.y - lo], 1u); col[p] = s.y; }
        if (d.z >= lo && d.z < hi) { uint32 p = atomicAdd(&cur[d.z - lo], 1u); col[p] = s.z; }
        if (d.w >= lo && d.w < hi) { uint32 p = atomicAdd(&cur[d.w - lo], 1u); col[p] = s.w; }
    }
}

// ---------------- tiny weight-collapse GEMMs ----------------
__global__ void k_w01(const float* __restrict__ W0, const float* __restrict__ W1,
                      float* __restrict__ W01) {
    __shared__ float row[NHID];
    int r = blockIdx.x, c = threadIdx.x;   // 128 threads
    row[c] = W0[r * NHID + c];
    __syncthreads();
    float acc = 0.f;
    for (int k = 0; k < NHID; k++) acc += row[k] * W1[k * NHID + c];
    W01[r * NHID + c] = acc;
}

__global__ void k_wc(const float* __restrict__ W01, const float* __restrict__ W2,
                     float* __restrict__ Wc) {
    __shared__ float row[NHID];
    int r = blockIdx.x, c = threadIdx.x;   // 64 threads
    row[c] = W01[r * NHID + c];
    row[c + 64] = W01[r * NHID + c + 64];
    __syncthreads();
    float acc = 0.f;
    for (int k = 0; k < NHID; k++) acc += row[k] * W2[k * NCLASS + c];
    Wc[r * NCLASS + c] = acc;
}

// bv[0..63] = b0@W1@W2, bv[64..127] = b1@W2
__global__ void k_bv(const float* __restrict__ b0, const float* __restrict__ W1,
                     const float* __restrict__ b1, const float* __restrict__ W2,
                     float* __restrict__ bv) {
    __shared__ float tmp[NHID];
    int c = threadIdx.x;   // 64 threads
    for (int cc = c; cc < NHID; cc += 64) {
        float a = 0.f;
        for (int k = 0; k < NHID; k++) a += b0[k] * W1[k * NHID + cc];
        tmp[cc] = a;
    }
    __syncthreads();
    float a1 = 0.f, a2 = 0.f;
    for (int k = 0; k < NHID; k++) {
        float w = W2[k * NCLASS + c];
        a1 += tmp[k] * w;
        a2 += b1[k] * w;
    }
    bv[c] = a1;
    bv[64 + c] = a2;
}

// ---------------- main GEMM: y = x @ Wc  [N,256]x[256,64] ----------------
__global__ void k_gemm_y(const float* __restrict__ x, const float* __restrict__ Wc,
                         float* __restrict__ y) {
    __shared__ float wc_sh[128 * NCLASS];   // 32 KB, staged in 2 halves of K
    __shared__ float x_sh[8][NFEAT];        // 8 KB
    int tid = threadIdx.x;
    int row0 = blockIdx.x * 8;
    for (int i = tid; i < 8 * NFEAT; i += 256) {
        int r = i >> 8, k = i & 255;
        int gr = row0 + r;
        x_sh[r][k] = (gr < N_NODES) ? x[gr * NFEAT + k] : 0.f;
    }
    int wid = tid >> 6, lane = tid & 63;
    float acc1 = 0.f, acc2 = 0.f;
    for (int half = 0; half < 2; half++) {
        __syncthreads();
        for (int i = tid; i < 128 * NCLASS; i += 256) wc_sh[i] = Wc[half * 128 * NCLASS + i];
        __syncthreads();
        const float* xr1 = &x_sh[wid][half * 128];
        const float* xr2 = &x_sh[wid + 4][half * 128];
#pragma unroll 4
        for (int k = 0; k < 128; k++) {
            float w = wc_sh[k * NCLASS + lane];
            acc1 += xr1[k] * w;
            acc2 += xr2[k] * w;
        }
    }
    int g1 = row0 + wid, g2 = row0 + wid + 4;
    if (g1 < N_NODES) y[g1 * NCLASS + lane] = acc1;
    if (g2 < N_NODES) y[g2 * NCLASS + lane] = acc2;
}

// ---------------- fused aggregation passes (unroll x8) ----------------
// One node per wave, lane = feature.
// PASS 1: out = Âin, tout = Â·1 ; PASS 2: out = Âin, tout = Â·tin
// PASS 3: out = softmax(Âin + t2*bv0 + t1*bv1 + b2)
template <int PASS>
__global__ __launch_bounds__(256) void k_agg(
        const int* __restrict__ row_ptr, const int* __restrict__ col,
        const float* __restrict__ n_src, const float* __restrict__ n_dst,
        const float* __restrict__ in, float* __restrict__ out,
        const float* __restrict__ tin, float* __restrict__ tout,
        const float* __restrict__ t1, const float* __restrict__ t2,
        const float* __restrict__ bv, const float* __restrict__ b2) {
    int wid = threadIdx.x >> 6, lane = threadIdx.x & 63;
    int node = blockIdx.x * 4 + wid;
    if (node >= N_NODES) return;
    int s = row_ptr[node], e = row_ptr[node + 1];
    float acc = 0.f, accs = 0.f;
    int p = s;
    for (; p + 8 <= e; p += 8) {
        int j0 = col[p],     j1 = col[p + 1], j2 = col[p + 2], j3 = col[p + 3];
        int j4 = col[p + 4], j5 = col[p + 5], j6 = col[p + 6], j7 = col[p + 7];
        float ns0 = n_src[j0], ns1 = n_src[j1], ns2 = n_src[j2], ns3 = n_src[j3];
        float ns4 = n_src[j4], ns5 = n_src[j5], ns6 = n_src[j6], ns7 = n_src[j7];
        float v0 = in[(size_t)j0 * NCLASS + lane];
        float v1 = in[(size_t)j1 * NCLASS + lane];
        float v2 = in[(size_t)j2 * NCLASS + lane];
        float v3 = in[(size_t)j3 * NCLASS + lane];
        float v4 = in[(size_t)j4 * NCLASS + lane];
        float v5 = in[(size_t)j5 * NCLASS + lane];
        float v6 = in[(size_t)j6 * NCLASS + lane];
        float v7 = in[(size_t)j7 * NCLASS + lane];
        acc += ns0 * v0 + ns1 * v1 + ns2 * v2 + ns3 * v3
             + ns4 * v4 + ns5 * v5 + ns6 * v6 + ns7 * v7;
        if (PASS == 1) accs += ns0 + ns1 + ns2 + ns3 + ns4 + ns5 + ns6 + ns7;
        if (PASS == 2) accs += ns0 * tin[j0] + ns1 * tin[j1] + ns2 * tin[j2] + ns3 * tin[j3]
                             + ns4 * tin[j4] + ns5 * tin[j5] + ns6 * tin[j6] + ns7 * tin[j7];
    }
    for (; p < e; p++) {
        int j = col[p];
        float ns = n_src[j];
        acc += ns * in[(size_t)j * NCLASS + lane];
        if (PASS == 1) accs += ns;
        if (PASS == 2) accs += ns * tin[j];
    }
    float nd = n_dst[node];
    if (PASS == 3) {
        float v = acc * nd + t2[node] * bv[lane] + t1[node] * bv[64 + lane] + b2[lane];
        float m = v;
        for (int o = 32; o >= 1; o >>= 1) m = fmaxf(m, __shfl_xor(m, o, 64));
        float ex = __expf(v - m);
        float sum = ex;
        for (int o = 32; o >= 1; o >>= 1) sum += __shfl_xor(sum, o, 64);
        out[(size_t)node * NCLASS + lane] = ex / sum;
    } else {
        out[(size_t)node * NCLASS + lane] = acc * nd;
        if (lane == 0) tout[node] = accs * nd;
    }
}

extern "C" void kernel_launch(void* const* d_in, const int* in_sizes, int n_in,
                              void* d_out, int out_size, void* d_ws, size_t ws_size,
                              hipStream_t stream) {
    const float* x   = (const float*)d_in[0];
    const int*   src = (const int*)d_in[1];
    const int*   dst = (const int*)d_in[2];
    const float* W0  = (const float*)d_in[3];
    const float* b0  = (const float*)d_in[4];
    const float* W1  = (const float*)d_in[5];
    const float* b1  = (const float*)d_in[6];
    const float* W2  = (const float*)d_in[7];
    const float* b2  = (const float*)d_in[8];
    float* out = (float*)d_out;

    size_t off = 0;
    auto alloc = [&](size_t bytes) {
        void* p = (char*)d_ws + off;
        off = (off + bytes + 255) & ~(size_t)255;
        return p;
    };
    int*    deg_in   = (int*)alloc(N_NODES * 4);
    float*  n_src    = (float*)alloc(N_NODES * 4);
    float*  n_dst    = (float*)alloc(N_NODES * 4);
    int*    row_ptr  = (int*)alloc((N_NODES + 1) * 4);
    int*    blk_sums = (int*)alloc((NB_SCAN + 1) * 4);
    int*    col      = (int*)alloc((size_t)N_EDGES * 4);
    uint32* scratch  = (uint32*)alloc((size_t)8 * NSL * RANGE * 4);   // 25.6 MB
    float*  W01      = (float*)alloc(NFEAT * NHID * 4);
    float*  Wc       = (float*)alloc(NFEAT * NCLASS * 4);
    float*  bv       = (float*)alloc(128 * 4);
    float*  t1       = (float*)alloc(N_NODES * 4);
    float*  t2       = (float*)alloc(N_NODES * 4);
    float*  bufA     = (float*)alloc((size_t)N_NODES * NCLASS * 4);
    (void)ws_size; (void)in_sizes; (void)n_in; (void)out_size;

    const int TB = 256;
    const int NBn = (N_NODES + TB - 1) / TB;
    const int NW = (N_NODES + 3) / 4;   // wave-per-node kernels
    const int GP = 8 * NSL;             // 512 blocks for hist/fill

    k_hist<<<GP, TB, 0, stream>>>((const int4*)src, (const int4*)dst, scratch);
    k_sumdeg<<<NBn, TB, 0, stream>>>(scratch, deg_in, n_src, n_dst);
    k_scan1<<<NB_SCAN, SCAN_B, 0, stream>>>(deg_in, row_ptr, blk_sums);
    k_scan2<<<1, 64, 0, stream>>>(blk_sums);
    k_scan3<<<NB_SCAN, SCAN_B, 0, stream>>>(blk_sums, row_ptr);
    k_offsets<<<NBn, TB, 0, stream>>>(scratch, row_ptr);
    k_fill2<<<GP, TB, 0, stream>>>((const int4*)src, (const int4*)dst, scratch, col);

    k_w01<<<NFEAT, NHID, 0, stream>>>(W0, W1, W01);
    k_wc<<<NFEAT, NCLASS, 0, stream>>>(W01, W2, Wc);
    k_bv<<<1, NCLASS, 0, stream>>>(b0, W1, b1, W2, bv);

    // Y -> bufA; Z1 -> OUT (+t1); Z2 -> bufA (+t2); pass3: bufA -> softmax -> OUT
    k_gemm_y<<<(N_NODES + 7) / 8, 256, 0, stream>>>(x, Wc, bufA);

    k_agg<1><<<NW, 256, 0, stream>>>(row_ptr, col, n_src, n_dst, bufA, out,
                                     nullptr, t1, nullptr, nullptr, nullptr, nullptr);
    k_agg<2><<<NW, 256, 0, stream>>>(row_ptr, col, n_src, n_dst, out, bufA,
                                     t1, t2, nullptr, nullptr, nullptr, nullptr);
    k_agg<3><<<NW, 256, 0, stream>>>(row_ptr, col, n_src, n_dst, bufA, out,
                                     nullptr, nullptr, t1, t2, bv, b2);
}

// Round 7
// 780.340 us; speedup vs baseline: 2.2254x; 1.0742x over previous
//
#include <hip/hip_runtime.h>
#include <hip/hip_bf16.h>

#define N_NODES 100000
#define N_EDGES 3200000
#define NFEAT 256
#define NHID 128
#define NCLASS 64
#define SCAN_B 1024
#define NB_SCAN ((N_NODES + SCAN_B - 1) / SCAN_B)   // 98
#define NVEC4 (N_EDGES / 4)                          // 800000
#define RANGE (N_NODES / 8)                          // 12500 nodes per group
#define NSL 64                                       // edge slices per group

typedef unsigned int uint32;

// ---------------- phase A: LDS-privatized histogram ----------------
__global__ __launch_bounds__(256) void k_hist(const int4* __restrict__ src4,
                                              const int4* __restrict__ dst4,
                                              uint32* __restrict__ scratch) {
    __shared__ uint32 h[RANGE];   // 50 KB
    int g = blockIdx.x & 7, sl = blockIdx.x >> 3;
    int lo = g * RANGE, hi = lo + RANGE;
    for (int i = threadIdx.x; i < RANGE; i += 256) h[i] = 0u;
    __syncthreads();
    for (int t = sl * 256 + threadIdx.x; t < NVEC4; t += NSL * 256) {
        int4 s = src4[t], d = dst4[t];
        if (s.x >= lo && s.x < hi) atomicAdd(&h[s.x - lo], 1u);
        if (s.y >= lo && s.y < hi) atomicAdd(&h[s.y - lo], 1u);
        if (s.z >= lo && s.z < hi) atomicAdd(&h[s.z - lo], 1u);
        if (s.w >= lo && s.w < hi) atomicAdd(&h[s.w - lo], 1u);
        if (d.x >= lo && d.x < hi) atomicAdd(&h[d.x - lo], 65536u);
        if (d.y >= lo && d.y < hi) atomicAdd(&h[d.y - lo], 65536u);
        if (d.z >= lo && d.z < hi) atomicAdd(&h[d.z - lo], 65536u);
        if (d.w >= lo && d.w < hi) atomicAdd(&h[d.w - lo], 65536u);
    }
    __syncthreads();
    uint32* dstp = scratch + ((size_t)(g * NSL + sl)) * RANGE;
    for (int i = threadIdx.x; i < RANGE; i += 256) dstp[i] = h[i];
}

// ---------------- reduce per-block counts -> degrees + norms ----------------
__global__ void k_sumdeg(const uint32* __restrict__ scratch, int* __restrict__ deg_in,
                         float* __restrict__ n_src, float* __restrict__ n_dst) {
    int i = blockIdx.x * blockDim.x + threadIdx.x;
    if (i >= N_NODES) return;
    int g = i / RANGE, r = i - g * RANGE;
    const uint32* base = scratch + (size_t)g * NSL * RANGE + r;
    uint32 so = 0, di = 0;
    for (int s = 0; s < NSL; s++) {
        uint32 v = base[(size_t)s * RANGE];
        so += v & 0xFFFFu;
        di += v >> 16;
    }
    deg_in[i] = (int)di;
    uint32 so1 = so < 1u ? 1u : so;
    uint32 di1 = di < 1u ? 1u : di;
    n_src[i] = rsqrtf((float)so1);
    n_dst[i] = rsqrtf((float)di1);
}

// ---------------- scan (3-pass) over deg_in -> row_ptr ----------------
__global__ void k_scan1(const int* __restrict__ deg_in, int* __restrict__ row_ptr,
                        int* __restrict__ blk_sums) {
    __shared__ int sh[SCAN_B];
    int i = blockIdx.x * SCAN_B + threadIdx.x;
    int v = (i < N_NODES) ? deg_in[i] : 0;
    sh[threadIdx.x] = v;
    __syncthreads();
    for (int o = 1; o < SCAN_B; o <<= 1) {
        int t = 0;
        if ((int)threadIdx.x >= o) t = sh[threadIdx.x - o];
        __syncthreads();
        sh[threadIdx.x] += t;
        __syncthreads();
    }
    if (i < N_NODES) row_ptr[i] = sh[threadIdx.x] - v;   // exclusive within block
    if (threadIdx.x == SCAN_B - 1) blk_sums[blockIdx.x] = sh[SCAN_B - 1];
}

__global__ void k_scan2(int* __restrict__ blk_sums) {
    if (threadIdx.x == 0 && blockIdx.x == 0) {
        int acc = 0;
        for (int b = 0; b < NB_SCAN; b++) { int v = blk_sums[b]; blk_sums[b] = acc; acc += v; }
        blk_sums[NB_SCAN] = acc;
    }
}

__global__ void k_scan3(const int* __restrict__ blk_sums, int* __restrict__ row_ptr) {
    int i = blockIdx.x * SCAN_B + threadIdx.x;
    if (i < N_NODES) row_ptr[i] += blk_sums[blockIdx.x];
    if (i == 0) row_ptr[N_NODES] = blk_sums[NB_SCAN];
}

// ---------------- per-(g,slice) cursor start offsets (in-place on scratch) ----------------
__global__ void k_offsets(uint32* __restrict__ scratch, const int* __restrict__ row_ptr) {
    int i = blockIdx.x * blockDim.x + threadIdx.x;
    if (i >= N_NODES) return;
    int g = i / RANGE, r = i - g * RANGE;
    uint32* base = scratch + (size_t)g * NSL * RANGE + r;
    uint32 run = (uint32)row_ptr[i];
    for (int s = 0; s < NSL; s++) {
        uint32 v = base[(size_t)s * RANGE];
        base[(size_t)s * RANGE] = run;
        run += v >> 16;
    }
}

// ---------------- phase B: atomic-free counting-sort fill ----------------
__global__ __launch_bounds__(256) void k_fill2(const int4* __restrict__ src4,
                                               const int4* __restrict__ dst4,
                                               const uint32* __restrict__ scratch,
                                               int* __restrict__ col) {
    __shared__ uint32 cur[RANGE];   // 50 KB
    int g = blockIdx.x & 7, sl = blockIdx.x >> 3;
    int lo = g * RANGE, hi = lo + RANGE;
    const uint32* base = scratch + ((size_t)(g * NSL + sl)) * RANGE;
    for (int i = threadIdx.x; i < RANGE; i += 256) cur[i] = base[i];
    __syncthreads();
    for (int t = sl * 256 + threadIdx.x; t < NVEC4; t += NSL * 256) {
        int4 s = src4[t], d = dst4[t];
        if (d.x >= lo && d.x < hi) { uint32 p = atomicAdd(&cur[d.x - lo], 1u); col[p] = s.x; }
        if (d.y >= lo && d.y < hi) { uint32 p = atomicAdd(&cur[d.y - lo], 1u); col[p] = s.y; }
        if (d.z >= lo && d.z < hi) { uint32 p = atomicAdd(&cur[d.z - lo], 1u); col[p] = s.z; }
        if (d.w >= lo && d.w < hi) { uint32 p = atomicAdd(&cur[d.w - lo], 1u); col[p] = s.w; }
    }
}

// ---------------- tiny weight-collapse GEMMs ----------------
__global__ void k_w01(const float* __restrict__ W0, const float* __restrict__ W1,
                      float* __restrict__ W01) {
    __shared__ float row[NHID];
    int r = blockIdx.x, c = threadIdx.x;   // 128 threads
    row[c] = W0[r * NHID + c];
    __syncthreads();
    float acc = 0.f;
    for (int k = 0; k < NHID; k++) acc += row[k] * W1[k * NHID + c];
    W01[r * NHID + c] = acc;
}

__global__ void k_wc(const float* __restrict__ W01, const float* __restrict__ W2,
                     float* __restrict__ Wc) {
    __shared__ float row[NHID];
    int r = blockIdx.x, c = threadIdx.x;   // 64 threads
    row[c] = W01[r * NHID + c];
    row[c + 64] = W01[r * NHID + c + 64];
    __syncthreads();
    float acc = 0.f;
    for (int k = 0; k < NHID; k++) acc += row[k] * W2[k * NCLASS + c];
    Wc[r * NCLASS + c] = acc;
}

// bv[0..63] = b0@W1@W2, bv[64..127] = b1@W2
__global__ void k_bv(const float* __restrict__ b0, const float* __restrict__ W1,
                     const float* __restrict__ b1, const float* __restrict__ W2,
                     float* __restrict__ bv) {
    __shared__ float tmp[NHID];
    int c = threadIdx.x;   // 64 threads
    for (int cc = c; cc < NHID; cc += 64) {
        float a = 0.f;
        for (int k = 0; k < NHID; k++) a += b0[k] * W1[k * NHID + cc];
        tmp[cc] = a;
    }
    __syncthreads();
    float a1 = 0.f, a2 = 0.f;
    for (int k = 0; k < NHID; k++) {
        float wv = W2[k * NCLASS + c];
        a1 += tmp[k] * wv;
        a2 += b1[k] * wv;
    }
    bv[c] = a1;
    bv[64 + c] = a2;
}

// ---------------- main GEMM: y = x @ Wc  [N,256]x[256,64] ----------------
// 64x64 tile/block; thread = 4 rows x 4 cols register tile. Wc staged once in
// LDS (64 KB, float4 reads); x streamed from global as float4 w/ prefetch.
static __device__ __forceinline__ void fma4(float4& a, float xs, const float4& wv) {
    a.x += xs * wv.x; a.y += xs * wv.y; a.z += xs * wv.z; a.w += xs * wv.w;
}
__global__ __launch_bounds__(256) void k_gemm_y(const float* __restrict__ x,
                                                const float* __restrict__ Wc,
                                                float* __restrict__ y) {
    __shared__ float w_sh[NFEAT][NCLASS];   // 64 KB
    int tid = threadIdx.x;
    {
        const float4* wsrc = (const float4*)Wc;
        float4* wdst = (float4*)&w_sh[0][0];
        for (int i = tid; i < NFEAT * NCLASS / 4; i += 256) wdst[i] = wsrc[i];
    }
    __syncthreads();
    int tx = tid & 15, ty = tid >> 4;
    int row0 = blockIdx.x * 64 + ty * 4;
    int c0 = tx * 4;
    int r0 = min(row0 + 0, N_NODES - 1);
    int r1 = min(row0 + 1, N_NODES - 1);
    int r2 = min(row0 + 2, N_NODES - 1);
    int r3 = min(row0 + 3, N_NODES - 1);
    const float* xp0 = x + (size_t)r0 * NFEAT;
    const float* xp1 = x + (size_t)r1 * NFEAT;
    const float* xp2 = x + (size_t)r2 * NFEAT;
    const float* xp3 = x + (size_t)r3 * NFEAT;
    float4 acc0 = {0, 0, 0, 0}, acc1 = {0, 0, 0, 0}, acc2 = {0, 0, 0, 0}, acc3 = {0, 0, 0, 0};
    float4 xa = *(const float4*)(xp0);
    float4 xb = *(const float4*)(xp1);
    float4 xc = *(const float4*)(xp2);
    float4 xd = *(const float4*)(xp3);
#pragma unroll 4
    for (int k = 0; k < NFEAT - 4; k += 4) {
        float4 ca = xa, cb = xb, cc = xc, cd = xd;
        xa = *(const float4*)(xp0 + k + 4);
        xb = *(const float4*)(xp1 + k + 4);
        xc = *(const float4*)(xp2 + k + 4);
        xd = *(const float4*)(xp3 + k + 4);
        float4 w0 = *(const float4*)&w_sh[k + 0][c0];
        float4 w1 = *(const float4*)&w_sh[k + 1][c0];
        float4 w2 = *(const float4*)&w_sh[k + 2][c0];
        float4 w3 = *(const float4*)&w_sh[k + 3][c0];
        fma4(acc0, ca.x, w0); fma4(acc0, ca.y, w1); fma4(acc0, ca.z, w2); fma4(acc0, ca.w, w3);
        fma4(acc1, cb.x, w0); fma4(acc1, cb.y, w1); fma4(acc1, cb.z, w2); fma4(acc1, cb.w, w3);
        fma4(acc2, cc.x, w0); fma4(acc2, cc.y, w1); fma4(acc2, cc.z, w2); fma4(acc2, cc.w, w3);
        fma4(acc3, cd.x, w0); fma4(acc3, cd.y, w1); fma4(acc3, cd.z, w2); fma4(acc3, cd.w, w3);
    }
    {
        const int k = NFEAT - 4;
        float4 w0 = *(const float4*)&w_sh[k + 0][c0];
        float4 w1 = *(const float4*)&w_sh[k + 1][c0];
        float4 w2 = *(const float4*)&w_sh[k + 2][c0];
        float4 w3 = *(const float4*)&w_sh[k + 3][c0];
        fma4(acc0, xa.x, w0); fma4(acc0, xa.y, w1); fma4(acc0, xa.z, w2); fma4(acc0, xa.w, w3);
        fma4(acc1, xb.x, w0); fma4(acc1, xb.y, w1); fma4(acc1, xb.z, w2); fma4(acc1, xb.w, w3);
        fma4(acc2, xc.x, w0); fma4(acc2, xc.y, w1); fma4(acc2, xc.z, w2); fma4(acc2, xc.w, w3);
        fma4(acc3, xd.x, w0); fma4(acc3, xd.y, w1); fma4(acc3, xd.z, w2); fma4(acc3, xd.w, w3);
    }
    if (row0 + 0 < N_NODES) *(float4*)(y + (size_t)(row0 + 0) * NCLASS + c0) = acc0;
    if (row0 + 1 < N_NODES) *(float4*)(y + (size_t)(row0 + 1) * NCLASS + c0) = acc1;
    if (row0 + 2 < N_NODES) *(float4*)(y + (size_t)(row0 + 2) * NCLASS + c0) = acc2;
    if (row0 + 3 < N_NODES) *(float4*)(y + (size_t)(row0 + 3) * NCLASS + c0) = acc3;
}

// ---------------- fused aggregation passes (unroll x8) ----------------
// PASS 1: out = Âin, tout = Â·1 ; PASS 2: out = Âin, tout = Â·tin
// PASS 3: out = softmax(Âin + t2*bv0 + t1*bv1 + b2)
template <int PASS>
__global__ __launch_bounds__(256) void k_agg(
        const int* __restrict__ row_ptr, const int* __restrict__ col,
        const float* __restrict__ n_src, const float* __restrict__ n_dst,
        const float* __restrict__ in, float* __restrict__ out,
        const float* __restrict__ tin, float* __restrict__ tout,
        const float* __restrict__ t1, const float* __restrict__ t2,
        const float* __restrict__ bv, const float* __restrict__ b2) {
    int wid = threadIdx.x >> 6, lane = threadIdx.x & 63;
    int node = blockIdx.x * 4 + wid;
    if (node >= N_NODES) return;
    int s = row_ptr[node], e = row_ptr[node + 1];
    float acc = 0.f, accs = 0.f;
    int p = s;
    for (; p + 8 <= e; p += 8) {
        int j0 = col[p],     j1 = col[p + 1], j2 = col[p + 2], j3 = col[p + 3];
        int j4 = col[p + 4], j5 = col[p + 5], j6 = col[p + 6], j7 = col[p + 7];
        float ns0 = n_src[j0], ns1 = n_src[j1], ns2 = n_src[j2], ns3 = n_src[j3];
        float ns4 = n_src[j4], ns5 = n_src[j5], ns6 = n_src[j6], ns7 = n_src[j7];
        float v0 = in[(size_t)j0 * NCLASS + lane];
        float v1 = in[(size_t)j1 * NCLASS + lane];
        float v2 = in[(size_t)j2 * NCLASS + lane];
        float v3 = in[(size_t)j3 * NCLASS + lane];
        float v4 = in[(size_t)j4 * NCLASS + lane];
        float v5 = in[(size_t)j5 * NCLASS + lane];
        float v6 = in[(size_t)j6 * NCLASS + lane];
        float v7 = in[(size_t)j7 * NCLASS + lane];
        acc += ns0 * v0 + ns1 * v1 + ns2 * v2 + ns3 * v3
             + ns4 * v4 + ns5 * v5 + ns6 * v6 + ns7 * v7;
        if (PASS == 1) accs += ns0 + ns1 + ns2 + ns3 + ns4 + ns5 + ns6 + ns7;
        if (PASS == 2) accs += ns0 * tin[j0] + ns1 * tin[j1] + ns2 * tin[j2] + ns3 * tin[j3]
                             + ns4 * tin[j4] + ns5 * tin[j5] + ns6 * tin[j6] + ns7 * tin[j7];
    }
    for (; p < e; p++) {
        int j = col[p];
        float ns = n_src[j];
        acc += ns * in[(size_t)j * NCLASS + lane];
        if (PASS == 1) accs += ns;
        if (PASS == 2) accs += ns * tin[j];
    }
    float nd = n_dst[node];
    if (PASS == 3) {
        float v = acc * nd + t2[node] * bv[lane] + t1[node] * bv[64 + lane] + b2[lane];
        float m = v;
        for (int o = 32; o >= 1; o >>= 1) m = fmaxf(m, __shfl_xor(m, o, 64));
        float ex = __expf(v - m);
        float sum = ex;
        for (int o = 32; o >= 1; o >>= 1) sum += __shfl_xor(sum, o, 64);
        out[(size_t)node * NCLASS + lane] = ex / sum;
    } else {
        out[(size_t)node * NCLASS + lane] = acc * nd;
        if (lane == 0) tout[node] = accs * nd;
    }
}

extern "C" void kernel_launch(void* const* d_in, const int* in_sizes, int n_in,
                              void* d_out, int out_size, void* d_ws, size_t ws_size,
                              hipStream_t stream) {
    const float* x   = (const float*)d_in[0];
    const int*   src = (const int*)d_in[1];
    const int*   dst = (const int*)d_in[2];
    const float* W0  = (const float*)d_in[3];
    const float* b0  = (const float*)d_in[4];
    const float* W1  = (const float*)d_in[5];
    const float* b1  = (const float*)d_in[6];
    const float* W2  = (const float*)d_in[7];
    const float* b2  = (const float*)d_in[8];
    float* out = (float*)d_out;

    size_t off = 0;
    auto alloc = [&](size_t bytes) {
        void* p = (char*)d_ws + off;
        off = (off + bytes + 255) & ~(size_t)255;
        return p;
    };
    int*    deg_in   = (int*)alloc(N_NODES * 4);
    float*  n_src    = (float*)alloc(N_NODES * 4);
    float*  n_dst    = (float*)alloc(N_NODES * 4);
    int*    row_ptr  = (int*)alloc((N_NODES + 1) * 4);
    int*    blk_sums = (int*)alloc((NB_SCAN + 1) * 4);
    int*    col      = (int*)alloc((size_t)N_EDGES * 4);
    uint32* scratch  = (uint32*)alloc((size_t)8 * NSL * RANGE * 4);   // 25.6 MB
    float*  W01      = (float*)alloc(NFEAT * NHID * 4);
    float*  Wc       = (float*)alloc(NFEAT * NCLASS * 4);
    float*  bv       = (float*)alloc(128 * 4);
    float*  t1       = (float*)alloc(N_NODES * 4);
    float*  t2       = (float*)alloc(N_NODES * 4);
    float*  bufA     = (float*)alloc((size_t)N_NODES * NCLASS * 4);
    (void)ws_size; (void)in_sizes; (void)n_in; (void)out_size;

    const int TB = 256;
    const int NBn = (N_NODES + TB - 1) / TB;
    const int NW = (N_NODES + 3) / 4;   // wave-per-node kernels
    const int GP = 8 * NSL;             // 512 blocks for hist/fill

    k_hist<<<GP, TB, 0, stream>>>((const int4*)src, (const int4*)dst, scratch);
    k_sumdeg<<<NBn, TB, 0, stream>>>(scratch, deg_in, n_src, n_dst);
    k_scan1<<<NB_SCAN, SCAN_B, 0, stream>>>(deg_in, row_ptr, blk_sums);
    k_scan2<<<1, 64, 0, stream>>>(blk_sums);
    k_scan3<<<NB_SCAN, SCAN_B, 0, stream>>>(blk_sums, row_ptr);
    k_offsets<<<NBn, TB, 0, stream>>>(scratch, row_ptr);
    k_fill2<<<GP, TB, 0, stream>>>((const int4*)src, (const int4*)dst, scratch, col);

    k_w01<<<NFEAT, NHID, 0, stream>>>(W0, W1, W01);
    k_wc<<<NFEAT, NCLASS, 0, stream>>>(W01, W2, Wc);
    k_bv<<<1, NCLASS, 0, stream>>>(b0, W1, b1, W2, bv);

    // Y -> bufA; Z1 -> OUT (+t1); Z2 -> bufA (+t2); pass3: bufA -> softmax -> OUT
    k_gemm_y<<<(N_NODES + 63) / 64, 256, 0, stream>>>(x, Wc, bufA);

    k_agg<1><<<NW, 256, 0, stream>>>(row_ptr, col, n_src, n_dst, bufA, out,
                                     nullptr, t1, nullptr, nullptr, nullptr, nullptr);
    k_agg<2><<<NW, 256, 0, stream>>>(row_ptr, col, n_src, n_dst, out, bufA,
                                     t1, t2, nullptr, nullptr, nullptr, nullptr);
    k_agg<3><<<NW, 256, 0, stream>>>(row_ptr, col, n_src, n_dst, bufA, out,
                                     nullptr, nullptr, t1, t2, bv, b2);
}

// Round 8
// 715.174 us; speedup vs baseline: 2.4281x; 1.0911x over previous
//
#include <hip/hip_runtime.h>
#include <hip/hip_bf16.h>

#define N_NODES 100000
#define N_EDGES 3200000
#define NFEAT 256
#define NHID 128
#define NCLASS 64
#define SCAN_B 1024
#define NB_SCAN ((N_NODES + SCAN_B - 1) / SCAN_B)   // 98
#define NVEC4 (N_EDGES / 4)                          // 800000
#define RANGE (N_NODES / 8)                          // 12500 nodes per group
#define NSL 64                                       // edge slices per group

typedef unsigned int uint32;
typedef unsigned short ushort16;

// hand-rolled bf16 (RNE) — intermediates only, finite values
static __device__ __forceinline__ float b2f(ushort16 u) {
    union { float f; uint32 i; } c; c.i = ((uint32)u) << 16; return c.f;
}
static __device__ __forceinline__ ushort16 f2b(float f) {
    union { float f; uint32 i; } c; c.f = f;
    uint32 r = (c.i + 0x7FFFu + ((c.i >> 16) & 1u)) >> 16;
    return (ushort16)r;
}

// ---------------- phase A: LDS-privatized histogram ----------------
__global__ __launch_bounds__(256) void k_hist(const int4* __restrict__ src4,
                                              const int4* __restrict__ dst4,
                                              uint32* __restrict__ scratch) {
    __shared__ uint32 h[RANGE];   // 50 KB
    int g = blockIdx.x & 7, sl = blockIdx.x >> 3;
    int lo = g * RANGE, hi = lo + RANGE;
    for (int i = threadIdx.x; i < RANGE; i += 256) h[i] = 0u;
    __syncthreads();
    for (int t = sl * 256 + threadIdx.x; t < NVEC4; t += NSL * 256) {
        int4 s = src4[t], d = dst4[t];
        if (s.x >= lo && s.x < hi) atomicAdd(&h[s.x - lo], 1u);
        if (s.y >= lo && s.y < hi) atomicAdd(&h[s.y - lo], 1u);
        if (s.z >= lo && s.z < hi) atomicAdd(&h[s.z - lo], 1u);
        if (s.w >= lo && s.w < hi) atomicAdd(&h[s.w - lo], 1u);
        if (d.x >= lo && d.x < hi) atomicAdd(&h[d.x - lo], 65536u);
        if (d.y >= lo && d.y < hi) atomicAdd(&h[d.y - lo], 65536u);
        if (d.z >= lo && d.z < hi) atomicAdd(&h[d.z - lo], 65536u);
        if (d.w >= lo && d.w < hi) atomicAdd(&h[d.w - lo], 65536u);
    }
    __syncthreads();
    uint32* dstp = scratch + ((size_t)(g * NSL + sl)) * RANGE;
    for (int i = threadIdx.x; i < RANGE; i += 256) dstp[i] = h[i];
}

// ---------------- reduce per-block counts -> degrees + norms ----------------
__global__ void k_sumdeg(const uint32* __restrict__ scratch, int* __restrict__ deg_in,
                         float* __restrict__ n_src, float* __restrict__ n_dst) {
    int i = blockIdx.x * blockDim.x + threadIdx.x;
    if (i >= N_NODES) return;
    int g = i / RANGE, r = i - g * RANGE;
    const uint32* base = scratch + (size_t)g * NSL * RANGE + r;
    uint32 so = 0, di = 0;
    for (int s = 0; s < NSL; s++) {
        uint32 v = base[(size_t)s * RANGE];
        so += v & 0xFFFFu;
        di += v >> 16;
    }
    deg_in[i] = (int)di;
    uint32 so1 = so < 1u ? 1u : so;
    uint32 di1 = di < 1u ? 1u : di;
    n_src[i] = rsqrtf((float)so1);
    n_dst[i] = rsqrtf((float)di1);
}

// ---------------- scan (3-pass) over deg_in -> row_ptr ----------------
__global__ void k_scan1(const int* __restrict__ deg_in, int* __restrict__ row_ptr,
                        int* __restrict__ blk_sums) {
    __shared__ int sh[SCAN_B];
    int i = blockIdx.x * SCAN_B + threadIdx.x;
    int v = (i < N_NODES) ? deg_in[i] : 0;
    sh[threadIdx.x] = v;
    __syncthreads();
    for (int o = 1; o < SCAN_B; o <<= 1) {
        int t = 0;
        if ((int)threadIdx.x >= o) t = sh[threadIdx.x - o];
        __syncthreads();
        sh[threadIdx.x] += t;
        __syncthreads();
    }
    if (i < N_NODES) row_ptr[i] = sh[threadIdx.x] - v;   // exclusive within block
    if (threadIdx.x == SCAN_B - 1) blk_sums[blockIdx.x] = sh[SCAN_B - 1];
}

__global__ void k_scan2(int* __restrict__ blk_sums) {
    if (threadIdx.x == 0 && blockIdx.x == 0) {
        int acc = 0;
        for (int b = 0; b < NB_SCAN; b++) { int v = blk_sums[b]; blk_sums[b] = acc; acc += v; }
        blk_sums[NB_SCAN] = acc;
    }
}

__global__ void k_scan3(const int* __restrict__ blk_sums, int* __restrict__ row_ptr) {
    int i = blockIdx.x * SCAN_B + threadIdx.x;
    if (i < N_NODES) row_ptr[i] += blk_sums[blockIdx.x];
    if (i == 0) row_ptr[N_NODES] = blk_sums[NB_SCAN];
}

// ---------------- per-(g,slice) cursor start offsets (in-place on scratch) ----------------
__global__ void k_offsets(uint32* __restrict__ scratch, const int* __restrict__ row_ptr) {
    int i = blockIdx.x * blockDim.x + threadIdx.x;
    if (i >= N_NODES) return;
    int g = i / RANGE, r = i - g * RANGE;
    uint32* base = scratch + (size_t)g * NSL * RANGE + r;
    uint32 run = (uint32)row_ptr[i];
    for (int s = 0; s < NSL; s++) {
        uint32 v = base[(size_t)s * RANGE];
        base[(size_t)s * RANGE] = run;
        run += v >> 16;
    }
}

// ---------------- phase B: atomic-free counting-sort fill ----------------
__global__ __launch_bounds__(256) void k_fill2(const int4* __restrict__ src4,
                                               const int4* __restrict__ dst4,
                                               const uint32* __restrict__ scratch,
                                               int* __restrict__ col) {
    __shared__ uint32 cur[RANGE];   // 50 KB
    int g = blockIdx.x & 7, sl = blockIdx.x >> 3;
    int lo = g * RANGE, hi = lo + RANGE;
    const uint32* base = scratch + ((size_t)(g * NSL + sl)) * RANGE;
    for (int i = threadIdx.x; i < RANGE; i += 256) cur[i] = base[i];
    __syncthreads();
    for (int t = sl * 256 + threadIdx.x; t < NVEC4; t += NSL * 256) {
        int4 s = src4[t], d = dst4[t];
        if (d.x >= lo && d.x < hi) { uint32 p = atomicAdd(&cur[d.x - lo], 1u); col[p] = s.x; }
        if (d.y >= lo && d.y < hi) { uint32 p = atomicAdd(&cur[d.y - lo], 1u); col[p] = s.y; }
        if (d.z >= lo && d.z < hi) { uint32 p = atomicAdd(&cur[d.z - lo], 1u); col[p] = s.z; }
        if (d.w >= lo && d.w < hi) { uint32 p = atomicAdd(&cur[d.w - lo], 1u); col[p] = s.w; }
    }
}

// ---------------- tiny weight-collapse GEMMs ----------------
__global__ void k_w01(const float* __restrict__ W0, const float* __restrict__ W1,
                      float* __restrict__ W01) {
    __shared__ float row[NHID];
    int r = blockIdx.x, c = threadIdx.x;   // 128 threads
    row[c] = W0[r * NHID + c];
    __syncthreads();
    float acc = 0.f;
    for (int k = 0; k < NHID; k++) acc += row[k] * W1[k * NHID + c];
    W01[r * NHID + c] = acc;
}

__global__ void k_wc(const float* __restrict__ W01, const float* __restrict__ W2,
                     float* __restrict__ Wc) {
    __shared__ float row[NHID];
    int r = blockIdx.x, c = threadIdx.x;   // 64 threads
    row[c] = W01[r * NHID + c];
    row[c + 64] = W01[r * NHID + c + 64];
    __syncthreads();
    float acc = 0.f;
    for (int k = 0; k < NHID; k++) acc += row[k] * W2[k * NCLASS + c];
    Wc[r * NCLASS + c] = acc;
}

// bv[0..63] = b0@W1@W2, bv[64..127] = b1@W2
__global__ void k_bv(const float* __restrict__ b0, const float* __restrict__ W1,
                     const float* __restrict__ b1, const float* __restrict__ W2,
                     float* __restrict__ bv) {
    __shared__ float tmp[NHID];
    int c = threadIdx.x;   // 64 threads
    for (int cc = c; cc < NHID; cc += 64) {
        float a = 0.f;
        for (int k = 0; k < NHID; k++) a += b0[k] * W1[k * NHID + cc];
        tmp[cc] = a;
    }
    __syncthreads();
    float a1 = 0.f, a2 = 0.f;
    for (int k = 0; k < NHID; k++) {
        float wv = W2[k * NCLASS + c];
        a1 += tmp[k] * wv;
        a2 += b1[k] * wv;
    }
    bv[c] = a1;
    bv[64 + c] = a2;
}

// ---------------- main GEMM: y = x @ Wc  [N,256]x[256,64], bf16 output ----------------
static __device__ __forceinline__ void fma4(float4& a, float xs, const float4& wv) {
    a.x += xs * wv.x; a.y += xs * wv.y; a.z += xs * wv.z; a.w += xs * wv.w;
}
__global__ __launch_bounds__(256) void k_gemm_y(const float* __restrict__ x,
                                                const float* __restrict__ Wc,
                                                ushort16* __restrict__ y) {
    __shared__ float w_sh[NFEAT][NCLASS];   // 64 KB
    int tid = threadIdx.x;
    {
        const float4* wsrc = (const float4*)Wc;
        float4* wdst = (float4*)&w_sh[0][0];
        for (int i = tid; i < NFEAT * NCLASS / 4; i += 256) wdst[i] = wsrc[i];
    }
    __syncthreads();
    int tx = tid & 15, ty = tid >> 4;
    int row0 = blockIdx.x * 64 + ty * 4;
    int c0 = tx * 4;
    int r0 = min(row0 + 0, N_NODES - 1);
    int r1 = min(row0 + 1, N_NODES - 1);
    int r2 = min(row0 + 2, N_NODES - 1);
    int r3 = min(row0 + 3, N_NODES - 1);
    const float* xp0 = x + (size_t)r0 * NFEAT;
    const float* xp1 = x + (size_t)r1 * NFEAT;
    const float* xp2 = x + (size_t)r2 * NFEAT;
    const float* xp3 = x + (size_t)r3 * NFEAT;
    float4 acc0 = {0, 0, 0, 0}, acc1 = {0, 0, 0, 0}, acc2 = {0, 0, 0, 0}, acc3 = {0, 0, 0, 0};
    float4 xa = *(const float4*)(xp0);
    float4 xb = *(const float4*)(xp1);
    float4 xc = *(const float4*)(xp2);
    float4 xd = *(const float4*)(xp3);
#pragma unroll 4
    for (int k = 0; k < NFEAT - 4; k += 4) {
        float4 ca = xa, cb = xb, cc = xc, cd = xd;
        xa = *(const float4*)(xp0 + k + 4);
        xb = *(const float4*)(xp1 + k + 4);
        xc = *(const float4*)(xp2 + k + 4);
        xd = *(const float4*)(xp3 + k + 4);
        float4 w0 = *(const float4*)&w_sh[k + 0][c0];
        float4 w1 = *(const float4*)&w_sh[k + 1][c0];
        float4 w2 = *(const float4*)&w_sh[k + 2][c0];
        float4 w3 = *(const float4*)&w_sh[k + 3][c0];
        fma4(acc0, ca.x, w0); fma4(acc0, ca.y, w1); fma4(acc0, ca.z, w2); fma4(acc0, ca.w, w3);
        fma4(acc1, cb.x, w0); fma4(acc1, cb.y, w1); fma4(acc1, cb.z, w2); fma4(acc1, cb.w, w3);
        fma4(acc2, cc.x, w0); fma4(acc2, cc.y, w1); fma4(acc2, cc.z, w2); fma4(acc2, cc.w, w3);
        fma4(acc3, cd.x, w0); fma4(acc3, cd.y, w1); fma4(acc3, cd.z, w2); fma4(acc3, cd.w, w3);
    }
    {
        const int k = NFEAT - 4;
        float4 w0 = *(const float4*)&w_sh[k + 0][c0];
        float4 w1 = *(const float4*)&w_sh[k + 1][c0];
        float4 w2 = *(const float4*)&w_sh[k + 2][c0];
        float4 w3 = *(const float4*)&w_sh[k + 3][c0];
        fma4(acc0, xa.x, w0); fma4(acc0, xa.y, w1); fma4(acc0, xa.z, w2); fma4(acc0, xa.w, w3);
        fma4(acc1, xb.x, w0); fma4(acc1, xb.y, w1); fma4(acc1, xb.z, w2); fma4(acc1, xb.w, w3);
        fma4(acc2, xc.x, w0); fma4(acc2, xc.y, w1); fma4(acc2, xc.z, w2); fma4(acc2, xc.w, w3);
        fma4(acc3, xd.x, w0); fma4(acc3, xd.y, w1); fma4(acc3, xd.z, w2); fma4(acc3, xd.w, w3);
    }
    ushort4 o0 = {f2b(acc0.x), f2b(acc0.y), f2b(acc0.z), f2b(acc0.w)};
    ushort4 o1 = {f2b(acc1.x), f2b(acc1.y), f2b(acc1.z), f2b(acc1.w)};
    ushort4 o2 = {f2b(acc2.x), f2b(acc2.y), f2b(acc2.z), f2b(acc2.w)};
    ushort4 o3 = {f2b(acc3.x), f2b(acc3.y), f2b(acc3.z), f2b(acc3.w)};
    if (row0 + 0 < N_NODES) *(ushort4*)(y + (size_t)(row0 + 0) * NCLASS + c0) = o0;
    if (row0 + 1 < N_NODES) *(ushort4*)(y + (size_t)(row0 + 1) * NCLASS + c0) = o1;
    if (row0 + 2 < N_NODES) *(ushort4*)(y + (size_t)(row0 + 2) * NCLASS + c0) = o2;
    if (row0 + 3 < N_NODES) *(ushort4*)(y + (size_t)(row0 + 3) * NCLASS + c0) = o3;
}

// ---------------- fused aggregation passes (bf16 gather, unroll x8) ----------------
// PASS 1: out = Âin, tout = Â·1 ; PASS 2: out = Âin, tout = Â·tin
// PASS 3: outf = softmax(Âin + t2*bv0 + t1*bv1 + b2)  (f32 output)
template <int PASS>
__global__ __launch_bounds__(256) void k_agg(
        const int* __restrict__ row_ptr, const int* __restrict__ col,
        const float* __restrict__ n_src, const float* __restrict__ n_dst,
        const ushort16* __restrict__ in, ushort16* __restrict__ out,
        float* __restrict__ outf,
        const float* __restrict__ tin, float* __restrict__ tout,
        const float* __restrict__ t1, const float* __restrict__ t2,
        const float* __restrict__ bv, const float* __restrict__ b2) {
    int wid = threadIdx.x >> 6, lane = threadIdx.x & 63;
    int node = blockIdx.x * 4 + wid;
    if (node >= N_NODES) return;
    int s = row_ptr[node], e = row_ptr[node + 1];
    float acc = 0.f, accs = 0.f;
    int p = s;
    for (; p + 8 <= e; p += 8) {
        int j0 = col[p],     j1 = col[p + 1], j2 = col[p + 2], j3 = col[p + 3];
        int j4 = col[p + 4], j5 = col[p + 5], j6 = col[p + 6], j7 = col[p + 7];
        float ns0 = n_src[j0], ns1 = n_src[j1], ns2 = n_src[j2], ns3 = n_src[j3];
        float ns4 = n_src[j4], ns5 = n_src[j5], ns6 = n_src[j6], ns7 = n_src[j7];
        ushort16 u0 = in[(size_t)j0 * NCLASS + lane];
        ushort16 u1 = in[(size_t)j1 * NCLASS + lane];
        ushort16 u2 = in[(size_t)j2 * NCLASS + lane];
        ushort16 u3 = in[(size_t)j3 * NCLASS + lane];
        ushort16 u4 = in[(size_t)j4 * NCLASS + lane];
        ushort16 u5 = in[(size_t)j5 * NCLASS + lane];
        ushort16 u6 = in[(size_t)j6 * NCLASS + lane];
        ushort16 u7 = in[(size_t)j7 * NCLASS + lane];
        acc += ns0 * b2f(u0) + ns1 * b2f(u1) + ns2 * b2f(u2) + ns3 * b2f(u3)
             + ns4 * b2f(u4) + ns5 * b2f(u5) + ns6 * b2f(u6) + ns7 * b2f(u7);
        if (PASS == 1) accs += ns0 + ns1 + ns2 + ns3 + ns4 + ns5 + ns6 + ns7;
        if (PASS == 2) accs += ns0 * tin[j0] + ns1 * tin[j1] + ns2 * tin[j2] + ns3 * tin[j3]
                             + ns4 * tin[j4] + ns5 * tin[j5] + ns6 * tin[j6] + ns7 * tin[j7];
    }
    for (; p < e; p++) {
        int j = col[p];
        float ns = n_src[j];
        acc += ns * b2f(in[(size_t)j * NCLASS + lane]);
        if (PASS == 1) accs += ns;
        if (PASS == 2) accs += ns * tin[j];
    }
    float nd = n_dst[node];
    if (PASS == 3) {
        float v = acc * nd + t2[node] * bv[lane] + t1[node] * bv[64 + lane] + b2[lane];
        float m = v;
        for (int o = 32; o >= 1; o >>= 1) m = fmaxf(m, __shfl_xor(m, o, 64));
        float ex = __expf(v - m);
        float sum = ex;
        for (int o = 32; o >= 1; o >>= 1) sum += __shfl_xor(sum, o, 64);
        outf[(size_t)node * NCLASS + lane] = ex / sum;
    } else {
        out[(size_t)node * NCLASS + lane] = f2b(acc * nd);
        if (lane == 0) tout[node] = accs * nd;
    }
}

extern "C" void kernel_launch(void* const* d_in, const int* in_sizes, int n_in,
                              void* d_out, int out_size, void* d_ws, size_t ws_size,
                              hipStream_t stream) {
    const float* x   = (const float*)d_in[0];
    const int*   src = (const int*)d_in[1];
    const int*   dst = (const int*)d_in[2];
    const float* W0  = (const float*)d_in[3];
    const float* b0  = (const float*)d_in[4];
    const float* W1  = (const float*)d_in[5];
    const float* b1  = (const float*)d_in[6];
    const float* W2  = (const float*)d_in[7];
    const float* b2  = (const float*)d_in[8];
    float* out = (float*)d_out;

    size_t off = 0;
    auto alloc = [&](size_t bytes) {
        void* p = (char*)d_ws + off;
        off = (off + bytes + 255) & ~(size_t)255;
        return p;
    };
    int*      deg_in   = (int*)alloc(N_NODES * 4);
    float*    n_src    = (float*)alloc(N_NODES * 4);
    float*    n_dst    = (float*)alloc(N_NODES * 4);
    int*      row_ptr  = (int*)alloc((N_NODES + 1) * 4);
    int*      blk_sums = (int*)alloc((NB_SCAN + 1) * 4);
    int*      col      = (int*)alloc((size_t)N_EDGES * 4);
    uint32*   scratch  = (uint32*)alloc((size_t)8 * NSL * RANGE * 4);   // 25.6 MB
    float*    W01      = (float*)alloc(NFEAT * NHID * 4);
    float*    Wc       = (float*)alloc(NFEAT * NCLASS * 4);
    float*    bv       = (float*)alloc(128 * 4);
    float*    t1       = (float*)alloc(N_NODES * 4);
    float*    t2       = (float*)alloc(N_NODES * 4);
    ushort16* bufB1    = (ushort16*)alloc((size_t)N_NODES * NCLASS * 2);  // 12.8 MB bf16
    ushort16* bufB2    = (ushort16*)alloc((size_t)N_NODES * NCLASS * 2);  // 12.8 MB bf16
    (void)ws_size; (void)in_sizes; (void)n_in; (void)out_size;

    const int TB = 256;
    const int NBn = (N_NODES + TB - 1) / TB;
    const int NW = (N_NODES + 3) / 4;   // wave-per-node kernels
    const int GP = 8 * NSL;             // 512 blocks for hist/fill

    k_hist<<<GP, TB, 0, stream>>>((const int4*)src, (const int4*)dst, scratch);
    k_sumdeg<<<NBn, TB, 0, stream>>>(scratch, deg_in, n_src, n_dst);
    k_scan1<<<NB_SCAN, SCAN_B, 0, stream>>>(deg_in, row_ptr, blk_sums);
    k_scan2<<<1, 64, 0, stream>>>(blk_sums);
    k_scan3<<<NB_SCAN, SCAN_B, 0, stream>>>(blk_sums, row_ptr);
    k_offsets<<<NBn, TB, 0, stream>>>(scratch, row_ptr);
    k_fill2<<<GP, TB, 0, stream>>>((const int4*)src, (const int4*)dst, scratch, col);

    k_w01<<<NFEAT, NHID, 0, stream>>>(W0, W1, W01);
    k_wc<<<NFEAT, NCLASS, 0, stream>>>(W01, W2, Wc);
    k_bv<<<1, NCLASS, 0, stream>>>(b0, W1, b1, W2, bv);

    // Y -> B1 (bf16); Z1 -> B2 (+t1); Z2 -> B1 (+t2); pass3: B1 -> softmax -> OUT (f32)
    k_gemm_y<<<(N_NODES + 63) / 64, 256, 0, stream>>>(x, Wc, bufB1);

    k_agg<1><<<NW, 256, 0, stream>>>(row_ptr, col, n_src, n_dst, bufB1, bufB2, nullptr,
                                     nullptr, t1, nullptr, nullptr, nullptr, nullptr);
    k_agg<2><<<NW, 256, 0, stream>>>(row_ptr, col, n_src, n_dst, bufB2, bufB1, nullptr,
                                     t1, t2, nullptr, nullptr, nullptr, nullptr);
    k_agg<3><<<NW, 256, 0, stream>>>(row_ptr, col, n_src, n_dst, bufB1, nullptr, out,
                                     nullptr, nullptr, t1, t2, bv, b2);
}